// Round 1
// baseline (863.342 us; speedup 1.0000x reference)
//
#include <hip/hip_runtime.h>
#include <math.h>

#define N_NODES 100000
#define N_EDGES 1600000
#define N_GRAPHS 256
#define T_CAPS 16
#define D_CH 64
#define BN_EPS 1e-5f

__device__ __forceinline__ float waveReduceSum(float v) {
    for (int m = 32; m >= 1; m >>= 1) v += __shfl_xor(v, m, 64);
    return v;
}

// ---- init: zero b_log, bn_sums; deg = 1.0 (self-loop weight) ----
__global__ void init_kernel(float* b_log, float* bn_sums, float* deg) {
    int idx = blockIdx.x * blockDim.x + threadIdx.x;
    if (idx < N_NODES * T_CAPS) b_log[idx] = 0.0f;
    if (idx < 128) bn_sums[idx] = 0.0f;
    if (idx < N_NODES) deg[idx] = 1.0f;
}

// ---- BN stats: per-channel sum & sumsq ----
__global__ void bn_stats_kernel(const float* __restrict__ x, float* __restrict__ sums) {
    int ch = threadIdx.x & 63;
    int rg = threadIdx.x >> 6;  // 0..3
    float s = 0.0f, s2 = 0.0f;
    for (int r = blockIdx.x * 4 + rg; r < N_NODES; r += gridDim.x * 4) {
        float v = x[r * 64 + ch];
        s += v; s2 += v * v;
    }
    __shared__ float ls[2][4][64];
    ls[0][rg][ch] = s; ls[1][rg][ch] = s2;
    __syncthreads();
    if (threadIdx.x < 64) {
        float a = 0.0f, b = 0.0f;
        for (int i = 0; i < 4; i++) { a += ls[0][i][threadIdx.x]; b += ls[1][i][threadIdx.x]; }
        atomicAdd(&sums[threadIdx.x], a);
        atomicAdd(&sums[64 + threadIdx.x], b);
    }
}

// ---- xn = (x - mu) / sqrt(var+eps) * gamma + beta ----
__global__ void xn_kernel(const float* __restrict__ x, const float* __restrict__ sums,
                          const float* __restrict__ gamma, const float* __restrict__ beta,
                          float* __restrict__ xn) {
    int idx = blockIdx.x * blockDim.x + threadIdx.x;
    if (idx >= N_NODES * D_CH) return;
    int ch = idx & 63;
    float mu = sums[ch] * (1.0f / N_NODES);
    float var = sums[64 + ch] * (1.0f / N_NODES) - mu * mu;
    float inv = 1.0f / sqrtf(var + BN_EPS);
    xn[idx] = (x[idx] - mu) * inv * gamma[ch] + beta[ch];
}

// ---- degree scatter: deg[col] += w ----
__global__ void edge_deg_kernel(const int* __restrict__ col, const float* __restrict__ ew,
                                float* __restrict__ deg) {
    int e = blockIdx.x * blockDim.x + threadIdx.x;
    if (e >= N_EDGES) return;
    atomicAdd(&deg[col[e]], ew[e]);
}

// ---- deg -> dinv in place ----
__global__ void dinv_kernel(float* __restrict__ deg) {
    int n = blockIdx.x * blockDim.x + threadIdx.x;
    if (n >= N_NODES) return;
    float d = deg[n];
    deg[n] = (d > 0.0f) ? 1.0f / sqrtf(d) : 0.0f;
}

// ---- h init with self-loop term: h = dinv^2 * xn ----
__global__ void h_init_kernel(const float* __restrict__ dinv, const float* __restrict__ xn,
                              float* __restrict__ h) {
    int idx = blockIdx.x * blockDim.x + threadIdx.x;
    if (idx >= N_NODES * D_CH) return;
    int n = idx >> 6;
    float dv = dinv[n];
    h[idx] = dv * dv * xn[idx];
}

// ---- edge scatter: h[col] += dinv[row]*w*dinv[col] * xn[row] ----
__global__ void h_scatter_kernel(const int* __restrict__ row, const int* __restrict__ col,
                                 const float* __restrict__ ew, const float* __restrict__ dinv,
                                 const float* __restrict__ xn, float* __restrict__ h) {
    long idx = (long)blockIdx.x * blockDim.x + threadIdx.x;
    if (idx >= (long)N_EDGES * 64) return;
    int e = (int)(idx >> 6), ch = (int)(idx & 63);
    int r = row[e], c = col[e];
    float coef = dinv[r] * ew[e] * dinv[c];
    atomicAdd(&h[c * 64 + ch], coef * xn[r * 64 + ch]);
}

// ---- graph segment offsets via binary search (batch is sorted) ----
__global__ void gstart_kernel(const int* __restrict__ batch, int* __restrict__ gstart) {
    int g = blockIdx.x * blockDim.x + threadIdx.x;
    if (g > N_GRAPHS) return;
    int lo = 0, hi = N_NODES;
    while (lo < hi) { int mid = (lo + hi) >> 1; if (batch[mid] < g) lo = mid + 1; else hi = mid; }
    gstart[g] = lo;
}

// ---- per-graph mean of xn ----
__global__ void xmean_kernel(const float* __restrict__ xn, const int* __restrict__ gstart,
                             float* __restrict__ xmean) {
    int g = blockIdx.x;
    int s0 = gstart[g], s1 = gstart[g + 1];
    int ch = threadIdx.x & 63, rg = threadIdx.x >> 6;
    float acc = 0.0f;
    for (int n = s0 + rg; n < s1; n += 4) acc += xn[n * 64 + ch];
    __shared__ float lds[4][64];
    lds[rg][ch] = acc;
    __syncthreads();
    if (threadIdx.x < 64) {
        float a = lds[0][threadIdx.x] + lds[1][threadIdx.x] + lds[2][threadIdx.x] + lds[3][threadIdx.x];
        int cnt = s1 - s0;
        xmean[g * 64 + threadIdx.x] = a / (float)(cnt > 1 ? cnt : 1);
    }
}

// ---- routing A: per-graph block; c = softmax_t(b_log); hc = sum c*h; csum = sum c ----
__global__ void ka_kernel(const float* __restrict__ b_log, const float* __restrict__ h,
                          const int* __restrict__ gstart, float* __restrict__ hc,
                          float* __restrict__ csum) {
    int g = blockIdx.x;
    int s0 = gstart[g], s1 = gstart[g + 1];
    int d = threadIdx.x & 63, tg = threadIdx.x >> 6;
    float acc0 = 0, acc1 = 0, acc2 = 0, acc3 = 0;
    float cs0 = 0, cs1 = 0, cs2 = 0, cs3 = 0;
    __shared__ float blds[16][16];
    __shared__ float clds[16][16];
    for (int n0 = s0; n0 < s1; n0 += 16) {
        int nn = min(16, s1 - n0);
        if ((int)threadIdx.x < nn * 16)
            ((float*)blds)[threadIdx.x] = b_log[n0 * 16 + (int)threadIdx.x];
        __syncthreads();
        if ((int)threadIdx.x < nn) {
            float m = -1e30f;
            for (int t = 0; t < 16; t++) m = fmaxf(m, blds[threadIdx.x][t]);
            float sum = 0.0f;
            for (int t = 0; t < 16; t++) { float e = expf(blds[threadIdx.x][t] - m); clds[threadIdx.x][t] = e; sum += e; }
            float inv = 1.0f / sum;
            for (int t = 0; t < 16; t++) clds[threadIdx.x][t] *= inv;
        }
        __syncthreads();
        for (int k = 0; k < nn; k++) {
            float hv = h[(n0 + k) * 64 + d];
            float c0 = clds[k][tg * 4 + 0], c1 = clds[k][tg * 4 + 1];
            float c2 = clds[k][tg * 4 + 2], c3 = clds[k][tg * 4 + 3];
            acc0 += c0 * hv; acc1 += c1 * hv; acc2 += c2 * hv; acc3 += c3 * hv;
            if (d == 0) { cs0 += c0; cs1 += c1; cs2 += c2; cs3 += c3; }
        }
        __syncthreads();
    }
    int base = (g * 16 + tg * 4) * 64 + d;
    hc[base] = acc0; hc[base + 64] = acc1; hc[base + 128] = acc2; hc[base + 192] = acc3;
    if (d == 0) {
        csum[g * 16 + tg * 4 + 0] = cs0; csum[g * 16 + tg * 4 + 1] = cs1;
        csum[g * 16 + tg * 4 + 2] = cs2; csum[g * 16 + tg * 4 + 3] = cs3;
    }
}

// ---- routing B: one wave per (g,t). s = hc@W_t + csum*bias_t (+xmean); v = squash(s).
//      mode 0: emit wv = W_t @ v, bv = bias_t . v;  mode 1: emit out = 1/sum(1/|v|) ----
__global__ void kb_kernel(const float* __restrict__ hc, const float* __restrict__ csum,
                          const float* __restrict__ W, const float* __restrict__ bias,
                          const float* __restrict__ xmean, float* __restrict__ wv,
                          float* __restrict__ bv, float* __restrict__ out, int final_mode) {
    int wid = blockIdx.x * 4 + (threadIdx.x >> 6);
    int lane = threadIdx.x & 63;
    int g = wid >> 4, t = wid & 15;
    const float* hcrow = hc + wid * 64;
    const float* Wt = W + t * 64 * 64;
    float s = csum[wid] * bias[t * 64 + lane];
    for (int i = 0; i < 64; i++) s += hcrow[i] * Wt[i * 64 + lane];
    if (final_mode) s += xmean[g * 64 + lane];
    float sq = waveReduceSum(s * s);
    float scale = (sq / (1.0f + sq)) / sqrtf(sq + 1e-16f);
    float v = scale * s;
    if (final_mode) {
        float tot = waveReduceSum(1.0f / fabsf(v));
        if (lane == 0) out[wid] = 1.0f / tot;
    } else {
        __shared__ float vlds[4][64];
        int w = threadIdx.x >> 6;
        vlds[w][lane] = v;
        __syncthreads();
        float acc = 0.0f;
        const float* Wrow = Wt + lane * 64;
        for (int o = 0; o < 64; o++) acc += Wrow[o] * vlds[w][o];
        wv[wid * 64 + lane] = acc;
        float b = waveReduceSum(bias[t * 64 + lane] * v);
        if (lane == 0) bv[wid] = b;
    }
}

// ---- routing C: b_log[n,t] += h[n] . wv[g,t] + bv[g,t] ----
__global__ void kc_kernel(float* __restrict__ b_log, const float* __restrict__ h,
                          const int* __restrict__ batch, const float* __restrict__ wv,
                          const float* __restrict__ bv) {
    int idx = blockIdx.x * blockDim.x + threadIdx.x;
    if (idx >= N_NODES * T_CAPS) return;
    int n = idx >> 4, t = idx & 15;
    int g = batch[n];
    const float* hrow = h + n * 64;
    const float* wrow = wv + (g * 16 + t) * 64;
    float acc = bv[g * 16 + t];
    for (int i = 0; i < 64; i++) acc += hrow[i] * wrow[i];
    b_log[idx] += acc;
}

extern "C" void kernel_launch(void* const* d_in, const int* in_sizes, int n_in,
                              void* d_out, int out_size, void* d_ws, size_t ws_size,
                              hipStream_t stream) {
    const float* x     = (const float*)d_in[0];
    const int*   ei    = (const int*)d_in[1];
    const float* ew    = (const float*)d_in[2];
    const int*   batch = (const int*)d_in[3];
    const float* gamma = (const float*)d_in[4];
    const float* beta  = (const float*)d_in[5];
    const float* W     = (const float*)d_in[6];
    const float* bias  = (const float*)d_in[7];
    float* out = (float*)d_out;

    const int* row = ei;
    const int* col = ei + N_EDGES;

    float* p = (float*)d_ws;
    float* xn      = p; p += N_NODES * D_CH;
    float* h       = p; p += N_NODES * D_CH;
    float* deg     = p; p += N_NODES;            // becomes dinv in place
    float* b_log   = p; p += N_NODES * T_CAPS;
    float* hc      = p; p += N_GRAPHS * T_CAPS * D_CH;
    float* csum    = p; p += N_GRAPHS * T_CAPS;
    float* wv      = p; p += N_GRAPHS * T_CAPS * D_CH;
    float* bv      = p; p += N_GRAPHS * T_CAPS;
    float* xmean   = p; p += N_GRAPHS * D_CH;
    float* bn_sums = p; p += 128;
    int*   gstart  = (int*)p;

    // init
    init_kernel<<<(N_NODES * T_CAPS + 255) / 256, 256, 0, stream>>>(b_log, bn_sums, deg);
    // BN
    bn_stats_kernel<<<512, 256, 0, stream>>>(x, bn_sums);
    xn_kernel<<<(N_NODES * D_CH + 255) / 256, 256, 0, stream>>>(x, bn_sums, gamma, beta, xn);
    // GCN degree + propagate
    edge_deg_kernel<<<(N_EDGES + 255) / 256, 256, 0, stream>>>(col, ew, deg);
    dinv_kernel<<<(N_NODES + 255) / 256, 256, 0, stream>>>(deg);
    h_init_kernel<<<(N_NODES * D_CH + 255) / 256, 256, 0, stream>>>(deg, xn, h);
    {
        long total = (long)N_EDGES * 64;
        int blocks = (int)((total + 255) / 256);
        h_scatter_kernel<<<blocks, 256, 0, stream>>>(row, col, ew, deg, xn, h);
    }
    // segments + per-graph mean
    gstart_kernel<<<2, 256, 0, stream>>>(batch, gstart);
    xmean_kernel<<<N_GRAPHS, 256, 0, stream>>>(xn, gstart, xmean);
    // dynamic routing: 2 update iterations + final
    for (int it = 0; it < 2; it++) {
        ka_kernel<<<N_GRAPHS, 256, 0, stream>>>(b_log, h, gstart, hc, csum);
        kb_kernel<<<N_GRAPHS * T_CAPS / 4, 256, 0, stream>>>(hc, csum, W, bias, xmean, wv, bv, out, 0);
        kc_kernel<<<(N_NODES * T_CAPS + 255) / 256, 256, 0, stream>>>(b_log, h, batch, wv, bv);
    }
    ka_kernel<<<N_GRAPHS, 256, 0, stream>>>(b_log, h, gstart, hc, csum);
    kb_kernel<<<N_GRAPHS * T_CAPS / 4, 256, 0, stream>>>(hc, csum, W, bias, xmean, wv, bv, out, 1);
}

// Round 2
// 737.030 us; speedup vs baseline: 1.1714x; 1.1714x over previous
//
#include <hip/hip_runtime.h>
#include <math.h>

#define N_NODES 100000
#define N_EDGES 1600000
#define N_GRAPHS 256
#define T_CAPS 16
#define D_CH 64
#define BN_EPS 1e-5f

__device__ __forceinline__ float waveReduceSum(float v) {
    for (int m = 32; m >= 1; m >>= 1) v += __shfl_xor(v, m, 64);
    return v;
}

// ---- init: zero b_log, bn_sums, cnt; deg = 1.0 (self-loop weight) ----
__global__ void init_kernel(float* b_log, float* bn_sums, float* deg, int* cnt) {
    int idx = blockIdx.x * blockDim.x + threadIdx.x;
    if (idx < N_NODES * T_CAPS) b_log[idx] = 0.0f;
    if (idx < 128) bn_sums[idx] = 0.0f;
    if (idx < N_NODES) { deg[idx] = 1.0f; cnt[idx] = 0; }
}

// ---- BN stats: per-channel sum & sumsq ----
__global__ void bn_stats_kernel(const float* __restrict__ x, float* __restrict__ sums) {
    int ch = threadIdx.x & 63;
    int rg = threadIdx.x >> 6;  // 0..3
    float s = 0.0f, s2 = 0.0f;
    for (int r = blockIdx.x * 4 + rg; r < N_NODES; r += gridDim.x * 4) {
        float v = x[r * 64 + ch];
        s += v; s2 += v * v;
    }
    __shared__ float ls[2][4][64];
    ls[0][rg][ch] = s; ls[1][rg][ch] = s2;
    __syncthreads();
    if (threadIdx.x < 64) {
        float a = 0.0f, b = 0.0f;
        for (int i = 0; i < 4; i++) { a += ls[0][i][threadIdx.x]; b += ls[1][i][threadIdx.x]; }
        atomicAdd(&sums[threadIdx.x], a);
        atomicAdd(&sums[64 + threadIdx.x], b);
    }
}

// ---- xn = (x - mu) / sqrt(var+eps) * gamma + beta ----
__global__ void xn_kernel(const float* __restrict__ x, const float* __restrict__ sums,
                          const float* __restrict__ gamma, const float* __restrict__ beta,
                          float* __restrict__ xn) {
    int idx = blockIdx.x * blockDim.x + threadIdx.x;
    if (idx >= N_NODES * D_CH) return;
    int ch = idx & 63;
    float mu = sums[ch] * (1.0f / N_NODES);
    float var = sums[64 + ch] * (1.0f / N_NODES) - mu * mu;
    float inv = 1.0f / sqrtf(var + BN_EPS);
    xn[idx] = (x[idx] - mu) * inv * gamma[ch] + beta[ch];
}

// ---- histogram pass: deg[col] += w; cnt[col] += 1 ----
__global__ void hist_kernel(const int* __restrict__ col, const float* __restrict__ ew,
                            float* __restrict__ deg, int* __restrict__ cnt) {
    int e = blockIdx.x * blockDim.x + threadIdx.x;
    if (e >= N_EDGES) return;
    int c = col[e];
    atomicAdd(&deg[c], ew[e]);
    atomicAdd(&cnt[c], 1);
}

// ---- deg -> dinv in place ----
__global__ void dinv_kernel(float* __restrict__ deg) {
    int n = blockIdx.x * blockDim.x + threadIdx.x;
    if (n >= N_NODES) return;
    float d = deg[n];
    deg[n] = (d > 0.0f) ? 1.0f / sqrtf(d) : 0.0f;
}

// ---- exclusive scan of cnt -> off, 1024 elems/block ----
__global__ void scan1_kernel(const int* __restrict__ cnt, int* __restrict__ off,
                             int* __restrict__ bsum) {
    __shared__ int lds[256];
    int tid = threadIdx.x;
    int base = blockIdx.x * 1024 + tid * 4;
    int c0 = (base + 0 < N_NODES) ? cnt[base + 0] : 0;
    int c1 = (base + 1 < N_NODES) ? cnt[base + 1] : 0;
    int c2 = (base + 2 < N_NODES) ? cnt[base + 2] : 0;
    int c3 = (base + 3 < N_NODES) ? cnt[base + 3] : 0;
    int tsum = c0 + c1 + c2 + c3;
    lds[tid] = tsum;
    __syncthreads();
    for (int d = 1; d < 256; d <<= 1) {
        int v = (tid >= d) ? lds[tid - d] : 0;
        __syncthreads();
        lds[tid] += v;
        __syncthreads();
    }
    int excl = lds[tid] - tsum;
    if (base + 0 < N_NODES) off[base + 0] = excl;
    if (base + 1 < N_NODES) off[base + 1] = excl + c0;
    if (base + 2 < N_NODES) off[base + 2] = excl + c0 + c1;
    if (base + 3 < N_NODES) off[base + 3] = excl + c0 + c1 + c2;
    if (tid == 255) bsum[blockIdx.x] = lds[255];
}

__global__ void scan2_kernel(int* __restrict__ bsum, int nb) {
    if (threadIdx.x == 0 && blockIdx.x == 0) {
        int s = 0;
        for (int i = 0; i < nb; i++) { int v = bsum[i]; bsum[i] = s; s += v; }
    }
}

__global__ void scan3_kernel(int* __restrict__ off, const int* __restrict__ bsum,
                             int* __restrict__ woff) {
    int idx = blockIdx.x * blockDim.x + threadIdx.x;
    if (idx < N_NODES) {
        int v = off[idx] + bsum[idx >> 10];
        off[idx] = v;
        woff[idx] = v;
    }
    if (idx == 0) off[N_NODES] = N_EDGES;
}

// ---- scatter edge records into CSR slots: rec[pos] = (row, coef) ----
__global__ void scatter_kernel(const int* __restrict__ row, const int* __restrict__ col,
                               const float* __restrict__ ew, const float* __restrict__ dinv,
                               int* __restrict__ woff, int2* __restrict__ rec) {
    int e = blockIdx.x * blockDim.x + threadIdx.x;
    if (e >= N_EDGES) return;
    int c = col[e], r = row[e];
    float coef = dinv[r] * ew[e] * dinv[c];
    int pos = atomicAdd(&woff[c], 1);
    rec[pos] = make_int2(r, __float_as_int(coef));
}

// ---- gather: h[n] = dinv[n]^2*xn[n] + sum_e coef*xn[row_e] (wave per node) ----
__global__ void h_gather_kernel(const int2* __restrict__ rec, const int* __restrict__ off,
                                const float* __restrict__ dinv, const float* __restrict__ xn,
                                float* __restrict__ h) {
    int n = blockIdx.x * 4 + (threadIdx.x >> 6);
    if (n >= N_NODES) return;
    int ch = threadIdx.x & 63;
    int e0 = off[n], e1 = off[n + 1];
    float dv = dinv[n];
    float acc = dv * dv * xn[n * 64 + ch];
    for (int e = e0; e < e1; ++e) {
        int2 rc = rec[e];
        acc += __int_as_float(rc.y) * xn[rc.x * 64 + ch];
    }
    h[n * 64 + ch] = acc;
}

// ---- graph segment offsets via binary search (batch is sorted) ----
__global__ void gstart_kernel(const int* __restrict__ batch, int* __restrict__ gstart) {
    int g = blockIdx.x * blockDim.x + threadIdx.x;
    if (g > N_GRAPHS) return;
    int lo = 0, hi = N_NODES;
    while (lo < hi) { int mid = (lo + hi) >> 1; if (batch[mid] < g) lo = mid + 1; else hi = mid; }
    gstart[g] = lo;
}

// ---- per-graph mean of xn ----
__global__ void xmean_kernel(const float* __restrict__ xn, const int* __restrict__ gstart,
                             float* __restrict__ xmean) {
    int g = blockIdx.x;
    int s0 = gstart[g], s1 = gstart[g + 1];
    int ch = threadIdx.x & 63, rg = threadIdx.x >> 6;
    float acc = 0.0f;
    for (int n = s0 + rg; n < s1; n += 4) acc += xn[n * 64 + ch];
    __shared__ float lds[4][64];
    lds[rg][ch] = acc;
    __syncthreads();
    if (threadIdx.x < 64) {
        float a = lds[0][threadIdx.x] + lds[1][threadIdx.x] + lds[2][threadIdx.x] + lds[3][threadIdx.x];
        int cnt = s1 - s0;
        xmean[g * 64 + threadIdx.x] = a / (float)(cnt > 1 ? cnt : 1);
    }
}

// ---- WT[t][o][i] = W[t][i][o] ----
__global__ void wt_prep_kernel(const float* __restrict__ W, float* __restrict__ WT) {
    int idx = blockIdx.x * blockDim.x + threadIdx.x;
    if (idx >= T_CAPS * 64 * 64) return;
    int t = idx >> 12, rem = idx & 4095, o = rem >> 6, i = rem & 63;
    WT[idx] = W[t * 4096 + i * 64 + o];
}

// ---- routing A: per-graph block; c = softmax_t(b_log); hc = sum c*h; csum = sum c ----
__global__ void ka_kernel(const float* __restrict__ b_log, const float* __restrict__ h,
                          const int* __restrict__ gstart, float* __restrict__ hc,
                          float* __restrict__ csum) {
    int g = blockIdx.x;
    int s0 = gstart[g], s1 = gstart[g + 1];
    int d = threadIdx.x & 63, tg = threadIdx.x >> 6;
    float acc0 = 0, acc1 = 0, acc2 = 0, acc3 = 0;
    float cs0 = 0, cs1 = 0, cs2 = 0, cs3 = 0;
    __shared__ float blds[16][16];
    __shared__ float clds[16][16];
    for (int n0 = s0; n0 < s1; n0 += 16) {
        int nn = min(16, s1 - n0);
        if ((int)threadIdx.x < nn * 16)
            ((float*)blds)[threadIdx.x] = b_log[n0 * 16 + (int)threadIdx.x];
        __syncthreads();
        if ((int)threadIdx.x < nn) {
            float m = -1e30f;
            for (int t = 0; t < 16; t++) m = fmaxf(m, blds[threadIdx.x][t]);
            float sum = 0.0f;
            for (int t = 0; t < 16; t++) { float e = expf(blds[threadIdx.x][t] - m); clds[threadIdx.x][t] = e; sum += e; }
            float inv = 1.0f / sum;
            for (int t = 0; t < 16; t++) clds[threadIdx.x][t] *= inv;
        }
        __syncthreads();
        for (int k = 0; k < nn; k++) {
            float hv = h[(n0 + k) * 64 + d];
            float c0 = clds[k][tg * 4 + 0], c1 = clds[k][tg * 4 + 1];
            float c2 = clds[k][tg * 4 + 2], c3 = clds[k][tg * 4 + 3];
            acc0 += c0 * hv; acc1 += c1 * hv; acc2 += c2 * hv; acc3 += c3 * hv;
            if (d == 0) { cs0 += c0; cs1 += c1; cs2 += c2; cs3 += c3; }
        }
        __syncthreads();
    }
    int base = (g * 16 + tg * 4) * 64 + d;
    hc[base] = acc0; hc[base + 64] = acc1; hc[base + 128] = acc2; hc[base + 192] = acc3;
    if (d == 0) {
        csum[g * 16 + tg * 4 + 0] = cs0; csum[g * 16 + tg * 4 + 1] = cs1;
        csum[g * 16 + tg * 4 + 2] = cs2; csum[g * 16 + tg * 4 + 3] = cs3;
    }
}

// ---- routing B: one wave per (g,t). s = hc@W_t + csum*bias_t (+xmean); v = squash(s).
//      mode 0: emit wvT[g][i][t] = (W_t v)[i], bv = bias_t . v;  mode 1: out = 1/sum(1/|v|) ----
__global__ void kb_kernel(const float* __restrict__ hc, const float* __restrict__ csum,
                          const float* __restrict__ W, const float* __restrict__ WT,
                          const float* __restrict__ bias, const float* __restrict__ xmean,
                          float* __restrict__ wvT, float* __restrict__ bv,
                          float* __restrict__ out, int final_mode) {
    int wid = blockIdx.x * 4 + (threadIdx.x >> 6);
    int lane = threadIdx.x & 63;
    int g = wid >> 4, t = wid & 15;
    const float* hcrow = hc + wid * 64;
    const float* Wt = W + t * 64 * 64;
    float s = csum[wid] * bias[t * 64 + lane];
    for (int i = 0; i < 64; i++) s += hcrow[i] * Wt[i * 64 + lane];
    if (final_mode) s += xmean[g * 64 + lane];
    float sq = waveReduceSum(s * s);
    float scale = (sq / (1.0f + sq)) / sqrtf(sq + 1e-16f);
    float v = scale * s;
    if (final_mode) {
        float tot = waveReduceSum(1.0f / fabsf(v));
        if (lane == 0) out[wid] = 1.0f / tot;
    } else {
        __shared__ float vlds[4][64];
        int w = threadIdx.x >> 6;
        vlds[w][lane] = v;
        __syncthreads();
        // wv[i=lane] = sum_o WT[t][o][i] * v[o]  (coalesced over i)
        const float* WTt = WT + t * 4096;
        float acc = 0.0f;
        for (int o = 0; o < 64; o++) acc += WTt[o * 64 + lane] * vlds[w][o];
        wvT[(g * 64 + lane) * 16 + t] = acc;
        float b = waveReduceSum(bias[t * 64 + lane] * v);
        if (lane == 0) bv[wid] = b;
    }
}

// ---- routing C: b_log[n,t] += h[n] . wv[g,t] + bv[g,t]  (wvT layout [g][i][t]) ----
__global__ void kc_kernel(float* __restrict__ b_log, const float* __restrict__ h,
                          const int* __restrict__ batch, const float* __restrict__ wvT,
                          const float* __restrict__ bv) {
    int idx = blockIdx.x * blockDim.x + threadIdx.x;
    if (idx >= N_NODES * T_CAPS) return;
    int n = idx >> 4, t = idx & 15;
    int g = batch[n];
    const float* hrow = h + n * 64;
    const float* wt = wvT + g * 1024 + t;
    float acc = bv[g * 16 + t];
    for (int i = 0; i < 64; i++) acc += hrow[i] * wt[i * 16];
    b_log[idx] += acc;
}

extern "C" void kernel_launch(void* const* d_in, const int* in_sizes, int n_in,
                              void* d_out, int out_size, void* d_ws, size_t ws_size,
                              hipStream_t stream) {
    const float* x     = (const float*)d_in[0];
    const int*   ei    = (const int*)d_in[1];
    const float* ew    = (const float*)d_in[2];
    const int*   batch = (const int*)d_in[3];
    const float* gamma = (const float*)d_in[4];
    const float* beta  = (const float*)d_in[5];
    const float* W     = (const float*)d_in[6];
    const float* bias  = (const float*)d_in[7];
    float* out = (float*)d_out;

    const int* row = ei;
    const int* col = ei + N_EDGES;

    // workspace layout (rec first for 8B alignment)
    char* base = (char*)d_ws;
    int2* rec = (int2*)base;                       base += sizeof(int2) * N_EDGES;
    float* p = (float*)base;
    float* xn      = p; p += N_NODES * D_CH;
    float* h       = p; p += N_NODES * D_CH;
    float* deg     = p; p += N_NODES;              // becomes dinv in place
    float* b_log   = p; p += N_NODES * T_CAPS;
    float* hc      = p; p += N_GRAPHS * T_CAPS * D_CH;
    float* csum    = p; p += N_GRAPHS * T_CAPS;
    float* wvT     = p; p += N_GRAPHS * D_CH * T_CAPS;
    float* bv      = p; p += N_GRAPHS * T_CAPS;
    float* xmean   = p; p += N_GRAPHS * D_CH;
    float* bn_sums = p; p += 128;
    float* WT      = p; p += T_CAPS * 64 * 64;
    int*   ip      = (int*)p;
    int*   off     = ip; ip += N_NODES + 1;
    int*   woff    = ip; ip += N_NODES;
    int*   bsum    = ip; ip += 128;
    int*   gstart  = ip; ip += N_GRAPHS + 1;
    int*   cnt     = ip; ip += N_NODES;

    // init
    init_kernel<<<(N_NODES * T_CAPS + 255) / 256, 256, 0, stream>>>(b_log, bn_sums, deg, cnt);
    // BN
    bn_stats_kernel<<<512, 256, 0, stream>>>(x, bn_sums);
    xn_kernel<<<(N_NODES * D_CH + 255) / 256, 256, 0, stream>>>(x, bn_sums, gamma, beta, xn);
    // degree + CSR build
    hist_kernel<<<(N_EDGES + 255) / 256, 256, 0, stream>>>(col, ew, deg, cnt);
    dinv_kernel<<<(N_NODES + 255) / 256, 256, 0, stream>>>(deg);
    scan1_kernel<<<(N_NODES + 1023) / 1024, 256, 0, stream>>>(cnt, off, bsum);
    scan2_kernel<<<1, 64, 0, stream>>>(bsum, (N_NODES + 1023) / 1024);
    scan3_kernel<<<(N_NODES + 255) / 256, 256, 0, stream>>>(off, bsum, woff);
    scatter_kernel<<<(N_EDGES + 255) / 256, 256, 0, stream>>>(row, col, ew, deg, woff, rec);
    // gather
    h_gather_kernel<<<N_NODES / 4, 256, 0, stream>>>(rec, off, deg, xn, h);
    // segments + per-graph mean + WT
    gstart_kernel<<<2, 256, 0, stream>>>(batch, gstart);
    xmean_kernel<<<N_GRAPHS, 256, 0, stream>>>(xn, gstart, xmean);
    wt_prep_kernel<<<(T_CAPS * 64 * 64 + 255) / 256, 256, 0, stream>>>(W, WT);
    // dynamic routing: 2 update iterations + final
    for (int it = 0; it < 2; it++) {
        ka_kernel<<<N_GRAPHS, 256, 0, stream>>>(b_log, h, gstart, hc, csum);
        kb_kernel<<<N_GRAPHS * T_CAPS / 4, 256, 0, stream>>>(hc, csum, W, WT, bias, xmean, wvT, bv, out, 0);
        kc_kernel<<<(N_NODES * T_CAPS + 255) / 256, 256, 0, stream>>>(b_log, h, batch, wvT, bv);
    }
    ka_kernel<<<N_GRAPHS, 256, 0, stream>>>(b_log, h, gstart, hc, csum);
    kb_kernel<<<N_GRAPHS * T_CAPS / 4, 256, 0, stream>>>(hc, csum, W, WT, bias, xmean, wvT, bv, out, 1);
}

// Round 3
// 685.746 us; speedup vs baseline: 1.2590x; 1.0748x over previous
//
#include <hip/hip_runtime.h>
#include <math.h>

#define N_NODES 100000
#define N_EDGES 1600000
#define N_GRAPHS 256
#define T_CAPS 16
#define D_CH 64
#define BN_EPS 1e-5f
#define NSPLIT 4

__device__ __forceinline__ float waveReduceSum(float v) {
    for (int m = 32; m >= 1; m >>= 1) v += __shfl_xor(v, m, 64);
    return v;
}

// ---- init: deg=1 (self-loop), cnt=0, zero bn_sums/hsum/xsum ----
__global__ void init_kernel(float* deg, int* cnt, float* bn_sums, float* hsum, float* xsum) {
    int idx = blockIdx.x * blockDim.x + threadIdx.x;
    if (idx < N_NODES) { deg[idx] = 1.0f; cnt[idx] = 0; }
    if (idx < 128) bn_sums[idx] = 0.0f;
    if (idx < N_GRAPHS * D_CH) { hsum[idx] = 0.0f; xsum[idx] = 0.0f; }
}

// ---- BN stats: per-channel sum & sumsq ----
__global__ void bn_stats_kernel(const float* __restrict__ x, float* __restrict__ sums) {
    int ch = threadIdx.x & 63;
    int rg = threadIdx.x >> 6;
    float s = 0.0f, s2 = 0.0f;
    for (int r = blockIdx.x * 4 + rg; r < N_NODES; r += gridDim.x * 4) {
        float v = x[r * 64 + ch];
        s += v; s2 += v * v;
    }
    __shared__ float ls[2][4][64];
    ls[0][rg][ch] = s; ls[1][rg][ch] = s2;
    __syncthreads();
    if (threadIdx.x < 64) {
        float a = 0.0f, b = 0.0f;
        for (int i = 0; i < 4; i++) { a += ls[0][i][threadIdx.x]; b += ls[1][i][threadIdx.x]; }
        atomicAdd(&sums[threadIdx.x], a);
        atomicAdd(&sums[64 + threadIdx.x], b);
    }
}

// ---- histogram: deg[col] += w; cnt[col] += 1 ----
__global__ void hist_kernel(const int* __restrict__ col, const float* __restrict__ ew,
                            float* __restrict__ deg, int* __restrict__ cnt) {
    int e = blockIdx.x * blockDim.x + threadIdx.x;
    if (e >= N_EDGES) return;
    int c = col[e];
    atomicAdd(&deg[c], ew[e]);
    atomicAdd(&cnt[c], 1);
}

// ---- deg -> dinv in place; also derive BN affine a,b into ab[0..63],ab[64..127] ----
__global__ void dinv_ab_kernel(float* __restrict__ deg, const float* __restrict__ sums,
                               const float* __restrict__ gamma, const float* __restrict__ beta,
                               float* __restrict__ ab) {
    int n = blockIdx.x * blockDim.x + threadIdx.x;
    if (n < 64) {
        float mu = sums[n] * (1.0f / N_NODES);
        float var = sums[64 + n] * (1.0f / N_NODES) - mu * mu;
        float inv = 1.0f / sqrtf(var + BN_EPS);
        float a = inv * gamma[n];
        ab[n] = a;
        ab[64 + n] = beta[n] - mu * a;
    }
    if (n < N_NODES) {
        float d = deg[n];
        deg[n] = (d > 0.0f) ? 1.0f / sqrtf(d) : 0.0f;
    }
}

// ---- exclusive scan of cnt -> off, 1024 elems/block ----
__global__ void scan1_kernel(const int* __restrict__ cnt, int* __restrict__ off,
                             int* __restrict__ bsum) {
    __shared__ int lds[256];
    int tid = threadIdx.x;
    int base = blockIdx.x * 1024 + tid * 4;
    int c0 = (base + 0 < N_NODES) ? cnt[base + 0] : 0;
    int c1 = (base + 1 < N_NODES) ? cnt[base + 1] : 0;
    int c2 = (base + 2 < N_NODES) ? cnt[base + 2] : 0;
    int c3 = (base + 3 < N_NODES) ? cnt[base + 3] : 0;
    int tsum = c0 + c1 + c2 + c3;
    lds[tid] = tsum;
    __syncthreads();
    for (int d = 1; d < 256; d <<= 1) {
        int v = (tid >= d) ? lds[tid - d] : 0;
        __syncthreads();
        lds[tid] += v;
        __syncthreads();
    }
    int excl = lds[tid] - tsum;
    if (base + 0 < N_NODES) off[base + 0] = excl;
    if (base + 1 < N_NODES) off[base + 1] = excl + c0;
    if (base + 2 < N_NODES) off[base + 2] = excl + c0 + c1;
    if (base + 3 < N_NODES) off[base + 3] = excl + c0 + c1 + c2;
    if (tid == 255) bsum[blockIdx.x] = lds[255];
}

// ---- scan of block sums (nb <= 128), one block ----
__global__ void scan2_kernel(int* __restrict__ bsum, int nb) {
    __shared__ int lds[128];
    int tid = threadIdx.x;
    int v = (tid < nb) ? bsum[tid] : 0;
    lds[tid] = v;
    __syncthreads();
    for (int d = 1; d < 128; d <<= 1) {
        int u = (tid >= d) ? lds[tid - d] : 0;
        __syncthreads();
        lds[tid] += u;
        __syncthreads();
    }
    if (tid < nb) bsum[tid] = lds[tid] - v;
}

__global__ void scan3_kernel(int* __restrict__ off, const int* __restrict__ bsum,
                             int* __restrict__ woff) {
    int idx = blockIdx.x * blockDim.x + threadIdx.x;
    if (idx < N_NODES) {
        int v = off[idx] + bsum[idx >> 10];
        off[idx] = v;
        woff[idx] = v;
    }
    if (idx == 0) off[N_NODES] = N_EDGES;
}

// ---- scatter edge records into CSR slots: rec[pos] = (row, coef) ----
__global__ void scatter_kernel(const int* __restrict__ row, const int* __restrict__ col,
                               const float* __restrict__ ew, const float* __restrict__ dinv,
                               int* __restrict__ woff, int2* __restrict__ rec) {
    int e = blockIdx.x * blockDim.x + threadIdx.x;
    if (e >= N_EDGES) return;
    int c = col[e], r = row[e];
    float coef = dinv[r] * ew[e] * dinv[c];
    int pos = atomicAdd(&woff[c], 1);
    rec[pos] = make_int2(r, __float_as_int(coef));
}

// ---- gather with BN folded in: h = a*(sum coef*x) + b*(sum coef); 4-way unroll ----
__global__ void h_gather_kernel(const int2* __restrict__ rec, const int* __restrict__ off,
                                const float* __restrict__ dinv, const float* __restrict__ x,
                                const float* __restrict__ ab, float* __restrict__ h) {
    int n = blockIdx.x * 4 + (threadIdx.x >> 6);
    int ch = threadIdx.x & 63;
    int e0 = off[n], e1 = off[n + 1];
    float dv = dinv[n];
    float cself = dv * dv;
    float acc0 = cself * x[n * 64 + ch], acc1 = 0.0f, acc2 = 0.0f, acc3 = 0.0f;
    float csr = cself;
    int e = e0;
    for (; e + 4 <= e1; e += 4) {
        int2 r0 = rec[e], r1 = rec[e + 1], r2 = rec[e + 2], r3 = rec[e + 3];
        float c0 = __int_as_float(r0.y), c1 = __int_as_float(r1.y);
        float c2 = __int_as_float(r2.y), c3 = __int_as_float(r3.y);
        float x0 = x[(size_t)r0.x * 64 + ch], x1 = x[(size_t)r1.x * 64 + ch];
        float x2 = x[(size_t)r2.x * 64 + ch], x3 = x[(size_t)r3.x * 64 + ch];
        acc0 += c0 * x0; acc1 += c1 * x1; acc2 += c2 * x2; acc3 += c3 * x3;
        csr += c0 + c1 + c2 + c3;
    }
    for (; e < e1; ++e) {
        int2 rc = rec[e];
        float c = __int_as_float(rc.y);
        acc0 += c * x[(size_t)rc.x * 64 + ch];
        csr += c;
    }
    float acc = (acc0 + acc1) + (acc2 + acc3);
    h[n * 64 + ch] = ab[ch] * acc + ab[64 + ch] * csr;
}

// ---- graph segment offsets via binary search (batch is sorted) ----
__global__ void gstart_kernel(const int* __restrict__ batch, int* __restrict__ gstart) {
    int g = blockIdx.x * blockDim.x + threadIdx.x;
    if (g > N_GRAPHS) return;
    int lo = 0, hi = N_NODES;
    while (lo < hi) { int mid = (lo + hi) >> 1; if (batch[mid] < g) lo = mid + 1; else hi = mid; }
    gstart[g] = lo;
}

// ---- per-graph sums of raw x and of h (atomic partials) ----
__global__ void gsum_kernel(const float* __restrict__ x, const float* __restrict__ h,
                            const int* __restrict__ gstart, float* __restrict__ xsum,
                            float* __restrict__ hsum) {
    int g = blockIdx.x / NSPLIT, sp = blockIdx.x % NSPLIT;
    int s0g = gstart[g], s1g = gstart[g + 1];
    int len = s1g - s0g;
    int q = (len + NSPLIT - 1) / NSPLIT;
    int a0 = s0g + sp * q, a1 = min(s1g, a0 + q);
    int ch = threadIdx.x & 63, rg = threadIdx.x >> 6;
    float ax = 0.0f, ah = 0.0f;
    for (int n = a0 + rg; n < a1; n += 4) { ax += x[n * 64 + ch]; ah += h[n * 64 + ch]; }
    __shared__ float lx[4][64], lh[4][64];
    lx[rg][ch] = ax; lh[rg][ch] = ah;
    __syncthreads();
    if (threadIdx.x < 64) {
        int c = threadIdx.x;
        float sx = lx[0][c] + lx[1][c] + lx[2][c] + lx[3][c];
        float sh = lh[0][c] + lh[1][c] + lh[2][c] + lh[3][c];
        atomicAdd(&xsum[g * 64 + c], sx);
        atomicAdd(&hsum[g * 64 + c], sh);
    }
}

// ---- WT[t][o][i] = W[t][i][o] ----
__global__ void wt_prep_kernel(const float* __restrict__ W, float* __restrict__ WT) {
    int idx = blockIdx.x * blockDim.x + threadIdx.x;
    if (idx >= T_CAPS * 64 * 64) return;
    int t = idx >> 12, rem = idx & 4095, o = rem >> 6, i = rem & 63;
    WT[idx] = W[t * 4096 + i * 64 + o];
}

// ---- fused routing update + softmax + weighted accumulate.
//      mode 0: b = h.wv + bv (write b_log); mode 1: b = b_log + h.wv + bv (no write).
//      emits hc_part[sp][g][t][d], csum_part[sp][g][t] ----
__global__ void ka_fused_kernel(const float* __restrict__ h, const int* __restrict__ gstart,
                                const float* __restrict__ wv, const float* __restrict__ bv,
                                float* __restrict__ b_log, float* __restrict__ hc_part,
                                float* __restrict__ csum_part, int mode) {
    int g = blockIdx.x / NSPLIT, sp = blockIdx.x % NSPLIT;
    int s0g = gstart[g], s1g = gstart[g + 1];
    int len = s1g - s0g;
    int q = (len + NSPLIT - 1) / NSPLIT;
    int s0 = s0g + sp * q, s1 = min(s1g, s0 + q);
    int d = threadIdx.x & 63, tg = threadIdx.x >> 6;
    float wv0 = wv[(g * 16 + tg * 4 + 0) * 64 + d];
    float wv1 = wv[(g * 16 + tg * 4 + 1) * 64 + d];
    float wv2 = wv[(g * 16 + tg * 4 + 2) * 64 + d];
    float wv3 = wv[(g * 16 + tg * 4 + 3) * 64 + d];
    float bv0 = bv[g * 16 + tg * 4 + 0];
    float bv1 = bv[g * 16 + tg * 4 + 1];
    float bv2 = bv[g * 16 + tg * 4 + 2];
    float bv3 = bv[g * 16 + tg * 4 + 3];
    float acc0 = 0, acc1 = 0, acc2 = 0, acc3 = 0;
    float cs0 = 0, cs1 = 0, cs2 = 0, cs3 = 0;
    __shared__ float hlds[16][64];
    __shared__ float clds[16][17];
    for (int n0 = s0; n0 < s1; n0 += 16) {
        int nn = min(16, s1 - n0);
        // stage h chunk in LDS (wave tg loads rows tg*4..tg*4+3)
        #pragma unroll
        for (int j = 0; j < 4; j++) {
            int k = tg * 4 + j;
            if (k < nn) hlds[k][d] = h[(size_t)(n0 + k) * 64 + d];
        }
        __syncthreads();
        // update logits: upd[k][t] = h[k].wv[t] + bv[t]
        for (int k = 0; k < nn; k++) {
            float hv = hlds[k][d];
            float u0 = waveReduceSum(hv * wv0);
            float u1 = waveReduceSum(hv * wv1);
            float u2 = waveReduceSum(hv * wv2);
            float u3 = waveReduceSum(hv * wv3);
            if (d == 0) {
                clds[k][tg * 4 + 0] = u0 + bv0;
                clds[k][tg * 4 + 1] = u1 + bv1;
                clds[k][tg * 4 + 2] = u2 + bv2;
                clds[k][tg * 4 + 3] = u3 + bv3;
            }
        }
        __syncthreads();
        // softmax per node (threads 0..nn-1)
        if ((int)threadIdx.x < nn) {
            int k = threadIdx.x;
            float b[16];
            #pragma unroll
            for (int t = 0; t < 16; t++) b[t] = clds[k][t];
            float4* bl = (float4*)(b_log + (size_t)(n0 + k) * 16);
            if (mode == 1) {
                float4 q0 = bl[0], q1 = bl[1], q2 = bl[2], q3 = bl[3];
                b[0] += q0.x; b[1] += q0.y; b[2] += q0.z; b[3] += q0.w;
                b[4] += q1.x; b[5] += q1.y; b[6] += q1.z; b[7] += q1.w;
                b[8] += q2.x; b[9] += q2.y; b[10] += q2.z; b[11] += q2.w;
                b[12] += q3.x; b[13] += q3.y; b[14] += q3.z; b[15] += q3.w;
            } else {
                bl[0] = make_float4(b[0], b[1], b[2], b[3]);
                bl[1] = make_float4(b[4], b[5], b[6], b[7]);
                bl[2] = make_float4(b[8], b[9], b[10], b[11]);
                bl[3] = make_float4(b[12], b[13], b[14], b[15]);
            }
            float m = -1e30f;
            #pragma unroll
            for (int t = 0; t < 16; t++) m = fmaxf(m, b[t]);
            float sum = 0.0f;
            #pragma unroll
            for (int t = 0; t < 16; t++) { float e = expf(b[t] - m); clds[k][t] = e; sum += e; }
            float inv = 1.0f / sum;
            #pragma unroll
            for (int t = 0; t < 16; t++) clds[k][t] *= inv;
        }
        __syncthreads();
        // accumulate hc += c * h
        for (int k = 0; k < nn; k++) {
            float hv = hlds[k][d];
            float c0 = clds[k][tg * 4 + 0], c1 = clds[k][tg * 4 + 1];
            float c2 = clds[k][tg * 4 + 2], c3 = clds[k][tg * 4 + 3];
            acc0 += c0 * hv; acc1 += c1 * hv; acc2 += c2 * hv; acc3 += c3 * hv;
            if (d == 0) { cs0 += c0; cs1 += c1; cs2 += c2; cs3 += c3; }
        }
        __syncthreads();
    }
    size_t base = ((size_t)(sp * N_GRAPHS + g) * 16 + tg * 4) * 64 + d;
    hc_part[base] = acc0; hc_part[base + 64] = acc1;
    hc_part[base + 128] = acc2; hc_part[base + 192] = acc3;
    if (d == 0) {
        int cb = (sp * N_GRAPHS + g) * 16 + tg * 4;
        csum_part[cb + 0] = cs0; csum_part[cb + 1] = cs1;
        csum_part[cb + 2] = cs2; csum_part[cb + 3] = cs3;
    }
}

// ---- kb: one wave per (g,t). mode 0: s = (hsum@W + cnt*bias)/16 (uniform first softmax).
//      mode 1: s = sum_sp hc_part @ W + csum*bias. mode 2: + xmean, emit out.
//      modes 0,1 emit wv = W_t @ v (via WT) and bv = bias_t . v ----
__global__ void kb_kernel(const float* __restrict__ hsum, const float* __restrict__ hc_part,
                          const float* __restrict__ csum_part, const float* __restrict__ W,
                          const float* __restrict__ WT, const float* __restrict__ bias,
                          const float* __restrict__ xsum, const float* __restrict__ ab,
                          const int* __restrict__ gstart, float* __restrict__ wv,
                          float* __restrict__ bv, float* __restrict__ out, int mode) {
    int wid = blockIdx.x * 4 + (threadIdx.x >> 6);
    int lane = threadIdx.x & 63;
    int g = wid >> 4, t = wid & 15;
    const float* Wt = W + t * 4096;
    float cnt = (float)(gstart[g + 1] - gstart[g]);
    float s;
    if (mode == 0) {
        const float* hr = hsum + g * 64;
        float acc = cnt * bias[t * 64 + lane];
        for (int i = 0; i < 64; i++) acc += hr[i] * Wt[i * 64 + lane];
        s = acc * (1.0f / 16.0f);
    } else {
        float csum = 0.0f;
        #pragma unroll
        for (int sp = 0; sp < NSPLIT; sp++) csum += csum_part[(sp * N_GRAPHS + g) * 16 + t];
        float acc = csum * bias[t * 64 + lane];
        for (int i = 0; i < 64; i++) {
            float hci = 0.0f;
            #pragma unroll
            for (int sp = 0; sp < NSPLIT; sp++)
                hci += hc_part[((size_t)(sp * N_GRAPHS + g) * 16 + t) * 64 + i];
            acc += hci * Wt[i * 64 + lane];
        }
        s = acc;
        if (mode == 2) {
            float xm = ab[lane] * xsum[g * 64 + lane] / fmaxf(cnt, 1.0f) + ab[64 + lane];
            s += xm;
        }
    }
    float sq = waveReduceSum(s * s);
    float scale = (sq / (1.0f + sq)) / sqrtf(sq + 1e-16f);
    float v = scale * s;
    if (mode == 2) {
        float tot = waveReduceSum(1.0f / fabsf(v));
        if (lane == 0) out[wid] = 1.0f / tot;
    } else {
        __shared__ float vlds[4][64];
        int w = threadIdx.x >> 6;
        vlds[w][lane] = v;
        __syncthreads();
        const float* WTt = WT + t * 4096;
        float acc = 0.0f;
        for (int o = 0; o < 64; o++) acc += WTt[o * 64 + lane] * vlds[w][o];
        wv[(size_t)wid * 64 + lane] = acc;
        float b = waveReduceSum(bias[t * 64 + lane] * v);
        if (lane == 0) bv[wid] = b;
    }
}

extern "C" void kernel_launch(void* const* d_in, const int* in_sizes, int n_in,
                              void* d_out, int out_size, void* d_ws, size_t ws_size,
                              hipStream_t stream) {
    const float* x     = (const float*)d_in[0];
    const int*   ei    = (const int*)d_in[1];
    const float* ew    = (const float*)d_in[2];
    const int*   batch = (const int*)d_in[3];
    const float* gamma = (const float*)d_in[4];
    const float* beta  = (const float*)d_in[5];
    const float* W     = (const float*)d_in[6];
    const float* bias  = (const float*)d_in[7];
    float* out = (float*)d_out;

    const int* row = ei;
    const int* col = ei + N_EDGES;

    char* basep = (char*)d_ws;
    int2* rec = (int2*)basep;                        basep += sizeof(int2) * N_EDGES;
    float* p = (float*)basep;
    float* h        = p; p += (size_t)N_NODES * D_CH;
    float* b_log    = p; p += (size_t)N_NODES * T_CAPS;
    float* hc_part  = p; p += (size_t)NSPLIT * N_GRAPHS * T_CAPS * D_CH;
    float* csum_part= p; p += NSPLIT * N_GRAPHS * T_CAPS;
    float* wv       = p; p += N_GRAPHS * T_CAPS * D_CH;
    float* bv       = p; p += N_GRAPHS * T_CAPS;
    float* WT       = p; p += T_CAPS * 64 * 64;
    float* deg      = p; p += N_NODES;               // becomes dinv in place
    float* bn_sums  = p; p += 128;
    float* ab       = p; p += 128;
    float* hsum     = p; p += N_GRAPHS * D_CH;
    float* xsum     = p; p += N_GRAPHS * D_CH;
    int*   ip       = (int*)p;
    int*   off      = ip; ip += N_NODES + 1;
    int*   woff     = ip; ip += N_NODES;
    int*   bsum     = ip; ip += 128;
    int*   gstart   = ip; ip += N_GRAPHS + 1;
    int*   cnt      = ip; ip += N_NODES;

    const int nscan = (N_NODES + 1023) / 1024;

    init_kernel<<<(N_NODES + 255) / 256, 256, 0, stream>>>(deg, cnt, bn_sums, hsum, xsum);
    gstart_kernel<<<2, 256, 0, stream>>>(batch, gstart);
    bn_stats_kernel<<<512, 256, 0, stream>>>(x, bn_sums);
    hist_kernel<<<(N_EDGES + 255) / 256, 256, 0, stream>>>(col, ew, deg, cnt);
    dinv_ab_kernel<<<(N_NODES + 255) / 256, 256, 0, stream>>>(deg, bn_sums, gamma, beta, ab);
    scan1_kernel<<<nscan, 256, 0, stream>>>(cnt, off, bsum);
    scan2_kernel<<<1, 128, 0, stream>>>(bsum, nscan);
    scan3_kernel<<<(N_NODES + 255) / 256, 256, 0, stream>>>(off, bsum, woff);
    scatter_kernel<<<(N_EDGES + 255) / 256, 256, 0, stream>>>(row, col, ew, deg, woff, rec);
    h_gather_kernel<<<N_NODES / 4, 256, 0, stream>>>(rec, off, deg, x, ab, h);
    gsum_kernel<<<N_GRAPHS * NSPLIT, 256, 0, stream>>>(x, h, gstart, xsum, hsum);
    wt_prep_kernel<<<(T_CAPS * 64 * 64 + 255) / 256, 256, 0, stream>>>(W, WT);

    // routing: kb(uniform) -> ka(upd1) -> kb -> ka(upd2) -> kb(final)
    kb_kernel<<<N_GRAPHS * T_CAPS / 4, 256, 0, stream>>>(hsum, hc_part, csum_part, W, WT, bias,
                                                          xsum, ab, gstart, wv, bv, out, 0);
    ka_fused_kernel<<<N_GRAPHS * NSPLIT, 256, 0, stream>>>(h, gstart, wv, bv, b_log,
                                                            hc_part, csum_part, 0);
    kb_kernel<<<N_GRAPHS * T_CAPS / 4, 256, 0, stream>>>(hsum, hc_part, csum_part, W, WT, bias,
                                                          xsum, ab, gstart, wv, bv, out, 1);
    ka_fused_kernel<<<N_GRAPHS * NSPLIT, 256, 0, stream>>>(h, gstart, wv, bv, b_log,
                                                            hc_part, csum_part, 1);
    kb_kernel<<<N_GRAPHS * T_CAPS / 4, 256, 0, stream>>>(hsum, hc_part, csum_part, W, WT, bias,
                                                          xsum, ab, gstart, wv, bv, out, 2);
}

// Round 4
// 486.657 us; speedup vs baseline: 1.7740x; 1.4091x over previous
//
#include <hip/hip_runtime.h>
#include <math.h>

#define N_NODES 100000
#define N_EDGES 1600000
#define N_GRAPHS 256
#define T_CAPS 16
#define D_CH 64
#define BN_EPS 1e-5f
#define NSPLIT 8
#define CHUNK 32

__device__ __forceinline__ float waveReduceSum(float v) {
    for (int m = 32; m >= 1; m >>= 1) v += __shfl_xor(v, m, 64);
    return v;
}

// ---- init: deg=1 (self-loop), cnt=0, zero bn_sums/hsum/xsum ----
__global__ void init_kernel(float* deg, int* cnt, float* bn_sums, float* hsum, float* xsum) {
    int idx = blockIdx.x * blockDim.x + threadIdx.x;
    if (idx < N_NODES) { deg[idx] = 1.0f; cnt[idx] = 0; }
    if (idx < 128) bn_sums[idx] = 0.0f;
    if (idx < N_GRAPHS * D_CH) { hsum[idx] = 0.0f; xsum[idx] = 0.0f; }
}

// ---- BN stats: per-channel sum & sumsq ----
__global__ void bn_stats_kernel(const float* __restrict__ x, float* __restrict__ sums) {
    int ch = threadIdx.x & 63;
    int rg = threadIdx.x >> 6;
    float s = 0.0f, s2 = 0.0f;
    for (int r = blockIdx.x * 4 + rg; r < N_NODES; r += gridDim.x * 4) {
        float v = x[r * 64 + ch];
        s += v; s2 += v * v;
    }
    __shared__ float ls[2][4][64];
    ls[0][rg][ch] = s; ls[1][rg][ch] = s2;
    __syncthreads();
    if (threadIdx.x < 64) {
        float a = 0.0f, b = 0.0f;
        for (int i = 0; i < 4; i++) { a += ls[0][i][threadIdx.x]; b += ls[1][i][threadIdx.x]; }
        atomicAdd(&sums[threadIdx.x], a);
        atomicAdd(&sums[64 + threadIdx.x], b);
    }
}

// ---- histogram: deg[col] += w; cnt[col] += 1 ----
__global__ void hist_kernel(const int* __restrict__ col, const float* __restrict__ ew,
                            float* __restrict__ deg, int* __restrict__ cnt) {
    int e = blockIdx.x * blockDim.x + threadIdx.x;
    if (e >= N_EDGES) return;
    int c = col[e];
    atomicAdd(&deg[c], ew[e]);
    atomicAdd(&cnt[c], 1);
}

// ---- deg -> dinv in place; also derive BN affine a,b into ab[0..63],ab[64..127] ----
__global__ void dinv_ab_kernel(float* __restrict__ deg, const float* __restrict__ sums,
                               const float* __restrict__ gamma, const float* __restrict__ beta,
                               float* __restrict__ ab) {
    int n = blockIdx.x * blockDim.x + threadIdx.x;
    if (n < 64) {
        float mu = sums[n] * (1.0f / N_NODES);
        float var = sums[64 + n] * (1.0f / N_NODES) - mu * mu;
        float inv = 1.0f / sqrtf(var + BN_EPS);
        float a = inv * gamma[n];
        ab[n] = a;
        ab[64 + n] = beta[n] - mu * a;
    }
    if (n < N_NODES) {
        float d = deg[n];
        deg[n] = (d > 0.0f) ? 1.0f / sqrtf(d) : 0.0f;
    }
}

// ---- exclusive scan of cnt -> off, 1024 elems/block ----
__global__ void scan1_kernel(const int* __restrict__ cnt, int* __restrict__ off,
                             int* __restrict__ bsum) {
    __shared__ int lds[256];
    int tid = threadIdx.x;
    int base = blockIdx.x * 1024 + tid * 4;
    int c0 = (base + 0 < N_NODES) ? cnt[base + 0] : 0;
    int c1 = (base + 1 < N_NODES) ? cnt[base + 1] : 0;
    int c2 = (base + 2 < N_NODES) ? cnt[base + 2] : 0;
    int c3 = (base + 3 < N_NODES) ? cnt[base + 3] : 0;
    int tsum = c0 + c1 + c2 + c3;
    lds[tid] = tsum;
    __syncthreads();
    for (int d = 1; d < 256; d <<= 1) {
        int v = (tid >= d) ? lds[tid - d] : 0;
        __syncthreads();
        lds[tid] += v;
        __syncthreads();
    }
    int excl = lds[tid] - tsum;
    if (base + 0 < N_NODES) off[base + 0] = excl;
    if (base + 1 < N_NODES) off[base + 1] = excl + c0;
    if (base + 2 < N_NODES) off[base + 2] = excl + c0 + c1;
    if (base + 3 < N_NODES) off[base + 3] = excl + c0 + c1 + c2;
    if (tid == 255) bsum[blockIdx.x] = lds[255];
}

// ---- scan of block sums (nb <= 128), one block ----
__global__ void scan2_kernel(int* __restrict__ bsum, int nb) {
    __shared__ int lds[128];
    int tid = threadIdx.x;
    int v = (tid < nb) ? bsum[tid] : 0;
    lds[tid] = v;
    __syncthreads();
    for (int d = 1; d < 128; d <<= 1) {
        int u = (tid >= d) ? lds[tid - d] : 0;
        __syncthreads();
        lds[tid] += u;
        __syncthreads();
    }
    if (tid < nb) bsum[tid] = lds[tid] - v;
}

__global__ void scan3_kernel(int* __restrict__ off, const int* __restrict__ bsum,
                             int* __restrict__ woff) {
    int idx = blockIdx.x * blockDim.x + threadIdx.x;
    if (idx < N_NODES) {
        int v = off[idx] + bsum[idx >> 10];
        off[idx] = v;
        woff[idx] = v;
    }
    if (idx == 0) off[N_NODES] = N_EDGES;
}

// ---- scatter edge records into CSR slots: rec[pos] = (row, coef) ----
__global__ void scatter_kernel(const int* __restrict__ row, const int* __restrict__ col,
                               const float* __restrict__ ew, const float* __restrict__ dinv,
                               int* __restrict__ woff, int2* __restrict__ rec) {
    int e = blockIdx.x * blockDim.x + threadIdx.x;
    if (e >= N_EDGES) return;
    int c = col[e], r = row[e];
    float coef = dinv[r] * ew[e] * dinv[c];
    int pos = atomicAdd(&woff[c], 1);
    rec[pos] = make_int2(r, __float_as_int(coef));
}

// ---- gather with BN folded in: h = a*(sum coef*x) + b*(sum coef); 4-way unroll ----
__global__ void h_gather_kernel(const int2* __restrict__ rec, const int* __restrict__ off,
                                const float* __restrict__ dinv, const float* __restrict__ x,
                                const float* __restrict__ ab, float* __restrict__ h) {
    int n = blockIdx.x * 4 + (threadIdx.x >> 6);
    int ch = threadIdx.x & 63;
    int e0 = off[n], e1 = off[n + 1];
    float dv = dinv[n];
    float cself = dv * dv;
    float acc0 = cself * x[n * 64 + ch], acc1 = 0.0f, acc2 = 0.0f, acc3 = 0.0f;
    float csr = cself;
    int e = e0;
    for (; e + 4 <= e1; e += 4) {
        int2 r0 = rec[e], r1 = rec[e + 1], r2 = rec[e + 2], r3 = rec[e + 3];
        float c0 = __int_as_float(r0.y), c1 = __int_as_float(r1.y);
        float c2 = __int_as_float(r2.y), c3 = __int_as_float(r3.y);
        float x0 = x[(size_t)r0.x * 64 + ch], x1 = x[(size_t)r1.x * 64 + ch];
        float x2 = x[(size_t)r2.x * 64 + ch], x3 = x[(size_t)r3.x * 64 + ch];
        acc0 += c0 * x0; acc1 += c1 * x1; acc2 += c2 * x2; acc3 += c3 * x3;
        csr += c0 + c1 + c2 + c3;
    }
    for (; e < e1; ++e) {
        int2 rc = rec[e];
        float c = __int_as_float(rc.y);
        acc0 += c * x[(size_t)rc.x * 64 + ch];
        csr += c;
    }
    float acc = (acc0 + acc1) + (acc2 + acc3);
    h[n * 64 + ch] = ab[ch] * acc + ab[64 + ch] * csr;
}

// ---- graph segment offsets via binary search (batch is sorted) ----
__global__ void gstart_kernel(const int* __restrict__ batch, int* __restrict__ gstart) {
    int g = blockIdx.x * blockDim.x + threadIdx.x;
    if (g > N_GRAPHS) return;
    int lo = 0, hi = N_NODES;
    while (lo < hi) { int mid = (lo + hi) >> 1; if (batch[mid] < g) lo = mid + 1; else hi = mid; }
    gstart[g] = lo;
}

// ---- per-graph sums of raw x and of h (atomic partials) ----
__global__ void gsum_kernel(const float* __restrict__ x, const float* __restrict__ h,
                            const int* __restrict__ gstart, float* __restrict__ xsum,
                            float* __restrict__ hsum) {
    int g = blockIdx.x / NSPLIT, sp = blockIdx.x % NSPLIT;
    int s0g = gstart[g], s1g = gstart[g + 1];
    int len = s1g - s0g;
    int q = (len + NSPLIT - 1) / NSPLIT;
    int a0 = s0g + sp * q, a1 = min(s1g, a0 + q);
    int ch = threadIdx.x & 63, rg = threadIdx.x >> 6;
    float ax = 0.0f, ah = 0.0f;
    for (int n = a0 + rg; n < a1; n += 4) { ax += x[n * 64 + ch]; ah += h[n * 64 + ch]; }
    __shared__ float lx[4][64], lh[4][64];
    lx[rg][ch] = ax; lh[rg][ch] = ah;
    __syncthreads();
    if (threadIdx.x < 64) {
        int c = threadIdx.x;
        float sx = lx[0][c] + lx[1][c] + lx[2][c] + lx[3][c];
        float sh = lh[0][c] + lh[1][c] + lh[2][c] + lh[3][c];
        atomicAdd(&xsum[g * 64 + c], sx);
        atomicAdd(&hsum[g * 64 + c], sh);
    }
}

// ---- WT[t][o][i] = W[t][i][o] ----
__global__ void wt_prep_kernel(const float* __restrict__ W, float* __restrict__ WT) {
    int idx = blockIdx.x * blockDim.x + threadIdx.x;
    if (idx >= T_CAPS * 64 * 64) return;
    int t = idx >> 12, rem = idx & 4095, o = rem >> 6, i = rem & 63;
    WT[idx] = W[t * 4096 + i * 64 + o];
}

// ---- fused routing: thread-parallel logit dot + in-register softmax + accumulate.
//      mode 0: logits = h.wva + bva.  mode 1: logits = (h.wva + bva) + (h.wvb + bvb).
//      emits hc_part[sp][g][t][d], csum_part[sp][g][t].  No b_log array needed. ----
__global__ void ka_fused_kernel(const float* __restrict__ h, const int* __restrict__ gstart,
                                const float* __restrict__ wva, const float* __restrict__ bva,
                                const float* __restrict__ wvb, const float* __restrict__ bvb,
                                float* __restrict__ hc_part, float* __restrict__ csum_part,
                                int mode) {
    int g = blockIdx.x / NSPLIT, sp = blockIdx.x % NSPLIT;
    int s0g = gstart[g], s1g = gstart[g + 1];
    int len = s1g - s0g;
    int q = (len + NSPLIT - 1) / NSPLIT;
    int s0 = s0g + sp * q, s1 = min(s1g, s0 + q);
    int tid = threadIdx.x;
    int d = tid & 63, tg = tid >> 6;   // accumulate-phase mapping
    int t = tid & 15, kh = tid >> 4;   // dot-phase mapping: this thread owns (kh, kh+16) x t

    __shared__ float hlds[CHUNK][65];
    __shared__ float wa[16][65];
    __shared__ float wb[16][65];
    __shared__ float clds[CHUNK][17];
    __shared__ float bvl[2][16];

    for (int i = tid; i < 16 * 64; i += 256) {
        int tt = i >> 6, dd = i & 63;
        wa[tt][dd] = wva[(g * 16 + tt) * 64 + dd];
        if (mode) wb[tt][dd] = wvb[(g * 16 + tt) * 64 + dd];
    }
    if (tid < 16) { bvl[0][tid] = bva[g * 16 + tid]; bvl[1][tid] = mode ? bvb[g * 16 + tid] : 0.0f; }
    // zero-fill hlds so out-of-range rows are benign
    for (int i = tid; i < CHUNK * 65; i += 256) ((float*)hlds)[i] = 0.0f;
    __syncthreads();

    float acc0 = 0, acc1 = 0, acc2 = 0, acc3 = 0;
    float cs0 = 0, cs1 = 0, cs2 = 0, cs3 = 0;

    for (int n0 = s0; n0 < s1; n0 += CHUNK) {
        int nn = min(CHUNK, s1 - n0);
        // stage h rows (each wave loads 8 rows)
        #pragma unroll
        for (int j = 0; j < 8; j++) {
            int k = tg * 8 + j;
            if (k < nn) hlds[k][d] = h[(size_t)(n0 + k) * 64 + d];
        }
        __syncthreads();
        // logit dot: u[k][t] = sum_d h[k][d]*wv[t][d] (+ b terms)
        int k0 = kh, k1 = kh + 16;
        float u0, u1;
        if (mode) {
            float a0 = bvl[0][t], a1 = bvl[0][t], b0 = bvl[1][t], b1 = bvl[1][t];
            for (int dd = 0; dd < 64; dd++) {
                float wav = wa[t][dd], wbv = wb[t][dd];
                float h0 = hlds[k0][dd], h1 = hlds[k1][dd];
                a0 += h0 * wav; a1 += h1 * wav;
                b0 += h0 * wbv; b1 += h1 * wbv;
            }
            u0 = a0 + b0; u1 = a1 + b1;
        } else {
            float a0 = bvl[0][t], a1 = bvl[0][t];
            for (int dd = 0; dd < 64; dd++) {
                float wav = wa[t][dd];
                a0 += hlds[k0][dd] * wav; a1 += hlds[k1][dd] * wav;
            }
            u0 = a0; u1 = a1;
        }
        // softmax over t within 16-lane groups (in-register butterfly)
        float m0 = u0, m1 = u1;
        #pragma unroll
        for (int msk = 1; msk < 16; msk <<= 1) {
            m0 = fmaxf(m0, __shfl_xor(m0, msk, 64));
            m1 = fmaxf(m1, __shfl_xor(m1, msk, 64));
        }
        float e0 = expf(u0 - m0), e1 = expf(u1 - m1);
        float z0 = e0, z1 = e1;
        #pragma unroll
        for (int msk = 1; msk < 16; msk <<= 1) {
            z0 += __shfl_xor(z0, msk, 64);
            z1 += __shfl_xor(z1, msk, 64);
        }
        if (k0 < nn) clds[k0][t] = e0 / z0;
        if (k1 < nn) clds[k1][t] = e1 / z1;
        __syncthreads();
        // accumulate hc += c * h
        for (int k = 0; k < nn; k++) {
            float hv = hlds[k][d];
            float c0 = clds[k][tg * 4 + 0], c1 = clds[k][tg * 4 + 1];
            float c2 = clds[k][tg * 4 + 2], c3 = clds[k][tg * 4 + 3];
            acc0 += c0 * hv; acc1 += c1 * hv; acc2 += c2 * hv; acc3 += c3 * hv;
            if (d == 0) { cs0 += c0; cs1 += c1; cs2 += c2; cs3 += c3; }
        }
        __syncthreads();
    }
    size_t base = ((size_t)(sp * N_GRAPHS + g) * 16 + tg * 4) * 64 + d;
    hc_part[base] = acc0; hc_part[base + 64] = acc1;
    hc_part[base + 128] = acc2; hc_part[base + 192] = acc3;
    if (d == 0) {
        int cb = (sp * N_GRAPHS + g) * 16 + tg * 4;
        csum_part[cb + 0] = cs0; csum_part[cb + 1] = cs1;
        csum_part[cb + 2] = cs2; csum_part[cb + 3] = cs3;
    }
}

// ---- kb: one wave per (g,t). mode 0: s = (hsum@W + cnt*bias)/16 (uniform first softmax).
//      mode 1: s = sum_sp hc_part @ W + csum*bias. mode 2: + xmean, emit out.
//      modes 0,1 emit wv = W_t @ v (via WT) and bv = bias_t . v into given buffers ----
__global__ void kb_kernel(const float* __restrict__ hsum, const float* __restrict__ hc_part,
                          const float* __restrict__ csum_part, const float* __restrict__ W,
                          const float* __restrict__ WT, const float* __restrict__ bias,
                          const float* __restrict__ xsum, const float* __restrict__ ab,
                          const int* __restrict__ gstart, float* __restrict__ wv,
                          float* __restrict__ bv, float* __restrict__ out, int mode) {
    int wid = blockIdx.x * 4 + (threadIdx.x >> 6);
    int lane = threadIdx.x & 63;
    int g = wid >> 4, t = wid & 15;
    const float* Wt = W + t * 4096;
    float cnt = (float)(gstart[g + 1] - gstart[g]);
    float s;
    if (mode == 0) {
        const float* hr = hsum + g * 64;
        float acc = cnt * bias[t * 64 + lane];
        for (int i = 0; i < 64; i++) acc += hr[i] * Wt[i * 64 + lane];
        s = acc * (1.0f / 16.0f);
    } else {
        float csum = 0.0f;
        #pragma unroll
        for (int sp = 0; sp < NSPLIT; sp++) csum += csum_part[(sp * N_GRAPHS + g) * 16 + t];
        float acc = csum * bias[t * 64 + lane];
        for (int i = 0; i < 64; i++) {
            float hci = 0.0f;
            #pragma unroll
            for (int sp = 0; sp < NSPLIT; sp++)
                hci += hc_part[((size_t)(sp * N_GRAPHS + g) * 16 + t) * 64 + i];
            acc += hci * Wt[i * 64 + lane];
        }
        s = acc;
        if (mode == 2) {
            float xm = ab[lane] * xsum[g * 64 + lane] / fmaxf(cnt, 1.0f) + ab[64 + lane];
            s += xm;
        }
    }
    float sq = waveReduceSum(s * s);
    float scale = (sq / (1.0f + sq)) / sqrtf(sq + 1e-16f);
    float v = scale * s;
    if (mode == 2) {
        float tot = waveReduceSum(1.0f / fabsf(v));
        if (lane == 0) out[wid] = 1.0f / tot;
    } else {
        __shared__ float vlds[4][64];
        int w = threadIdx.x >> 6;
        vlds[w][lane] = v;
        __syncthreads();
        const float* WTt = WT + t * 4096;
        float acc = 0.0f;
        for (int o = 0; o < 64; o++) acc += WTt[o * 64 + lane] * vlds[w][o];
        wv[(size_t)wid * 64 + lane] = acc;
        float b = waveReduceSum(bias[t * 64 + lane] * v);
        if (lane == 0) bv[wid] = b;
    }
}

extern "C" void kernel_launch(void* const* d_in, const int* in_sizes, int n_in,
                              void* d_out, int out_size, void* d_ws, size_t ws_size,
                              hipStream_t stream) {
    const float* x     = (const float*)d_in[0];
    const int*   ei    = (const int*)d_in[1];
    const float* ew    = (const float*)d_in[2];
    const int*   batch = (const int*)d_in[3];
    const float* gamma = (const float*)d_in[4];
    const float* beta  = (const float*)d_in[5];
    const float* W     = (const float*)d_in[6];
    const float* bias  = (const float*)d_in[7];
    float* out = (float*)d_out;

    const int* row = ei;
    const int* col = ei + N_EDGES;

    char* basep = (char*)d_ws;
    int2* rec = (int2*)basep;                        basep += sizeof(int2) * N_EDGES;
    float* p = (float*)basep;
    float* h        = p; p += (size_t)N_NODES * D_CH;
    float* hc_part  = p; p += (size_t)NSPLIT * N_GRAPHS * T_CAPS * D_CH;
    float* csum_part= p; p += NSPLIT * N_GRAPHS * T_CAPS;
    float* wva      = p; p += N_GRAPHS * T_CAPS * D_CH;
    float* bva      = p; p += N_GRAPHS * T_CAPS;
    float* wvb      = p; p += N_GRAPHS * T_CAPS * D_CH;
    float* bvb      = p; p += N_GRAPHS * T_CAPS;
    float* WT       = p; p += T_CAPS * 64 * 64;
    float* deg      = p; p += N_NODES;               // becomes dinv in place
    float* bn_sums  = p; p += 128;
    float* ab       = p; p += 128;
    float* hsum     = p; p += N_GRAPHS * D_CH;
    float* xsum     = p; p += N_GRAPHS * D_CH;
    int*   ip       = (int*)p;
    int*   off      = ip; ip += N_NODES + 1;
    int*   woff     = ip; ip += N_NODES;
    int*   bsum     = ip; ip += 128;
    int*   gstart   = ip; ip += N_GRAPHS + 1;
    int*   cnt      = ip; ip += N_NODES;

    const int nscan = (N_NODES + 1023) / 1024;

    init_kernel<<<(N_NODES + 255) / 256, 256, 0, stream>>>(deg, cnt, bn_sums, hsum, xsum);
    gstart_kernel<<<2, 256, 0, stream>>>(batch, gstart);
    bn_stats_kernel<<<512, 256, 0, stream>>>(x, bn_sums);
    hist_kernel<<<(N_EDGES + 255) / 256, 256, 0, stream>>>(col, ew, deg, cnt);
    dinv_ab_kernel<<<(N_NODES + 255) / 256, 256, 0, stream>>>(deg, bn_sums, gamma, beta, ab);
    scan1_kernel<<<nscan, 256, 0, stream>>>(cnt, off, bsum);
    scan2_kernel<<<1, 128, 0, stream>>>(bsum, nscan);
    scan3_kernel<<<(N_NODES + 255) / 256, 256, 0, stream>>>(off, bsum, woff);
    scatter_kernel<<<(N_EDGES + 255) / 256, 256, 0, stream>>>(row, col, ew, deg, woff, rec);
    h_gather_kernel<<<N_NODES / 4, 256, 0, stream>>>(rec, off, deg, x, ab, h);
    gsum_kernel<<<N_GRAPHS * NSPLIT, 256, 0, stream>>>(x, h, gstart, xsum, hsum);
    wt_prep_kernel<<<(T_CAPS * 64 * 64 + 255) / 256, 256, 0, stream>>>(W, WT);

    // routing: kb(uniform)->wva; ka(wva); kb->wvb; ka(wva+wvb); kb(final)
    kb_kernel<<<N_GRAPHS * T_CAPS / 4, 256, 0, stream>>>(hsum, hc_part, csum_part, W, WT, bias,
                                                          xsum, ab, gstart, wva, bva, out, 0);
    ka_fused_kernel<<<N_GRAPHS * NSPLIT, 256, 0, stream>>>(h, gstart, wva, bva, wvb, bvb,
                                                            hc_part, csum_part, 0);
    kb_kernel<<<N_GRAPHS * T_CAPS / 4, 256, 0, stream>>>(hsum, hc_part, csum_part, W, WT, bias,
                                                          xsum, ab, gstart, wvb, bvb, out, 1);
    ka_fused_kernel<<<N_GRAPHS * NSPLIT, 256, 0, stream>>>(h, gstart, wva, bva, wvb, bvb,
                                                            hc_part, csum_part, 1);
    kb_kernel<<<N_GRAPHS * T_CAPS / 4, 256, 0, stream>>>(hsum, hc_part, csum_part, W, WT, bias,
                                                          xsum, ab, gstart, wva, bva, out, 2);
}

// Round 5
// 362.464 us; speedup vs baseline: 2.3819x; 1.3426x over previous
//
#include <hip/hip_runtime.h>
#include <math.h>

#define N_NODES 100000
#define N_EDGES 1600000
#define N_GRAPHS 256
#define T_CAPS 16
#define D_CH 64
#define BN_EPS 1e-5f
#define NSPLIT 8
#define CHUNK 32
#define FIX_SCALE 33554432.0f   // 2^25

__device__ __forceinline__ float waveReduceSum(float v) {
    for (int m = 32; m >= 1; m >>= 1) v += __shfl_xor(v, m, 64);
    return v;
}

// ---- init: pack=0, zero bn_sums/hsum/xsum ----
__global__ void init_kernel(unsigned long long* pack, float* bn_sums, float* hsum, float* xsum) {
    int idx = blockIdx.x * blockDim.x + threadIdx.x;
    if (idx < N_NODES) pack[idx] = 0ULL;
    if (idx < 128) bn_sums[idx] = 0.0f;
    if (idx < N_GRAPHS * D_CH) { hsum[idx] = 0.0f; xsum[idx] = 0.0f; }
}

// ---- BN stats: per-channel sum & sumsq ----
__global__ void bn_stats_kernel(const float* __restrict__ x, float* __restrict__ sums) {
    int ch = threadIdx.x & 63;
    int rg = threadIdx.x >> 6;
    float s = 0.0f, s2 = 0.0f;
    for (int r = blockIdx.x * 4 + rg; r < N_NODES; r += gridDim.x * 4) {
        float v = x[r * 64 + ch];
        s += v; s2 += v * v;
    }
    __shared__ float ls[2][4][64];
    ls[0][rg][ch] = s; ls[1][rg][ch] = s2;
    __syncthreads();
    if (threadIdx.x < 64) {
        float a = 0.0f, b = 0.0f;
        for (int i = 0; i < 4; i++) { a += ls[0][i][threadIdx.x]; b += ls[1][i][threadIdx.x]; }
        atomicAdd(&sums[threadIdx.x], a);
        atomicAdd(&sums[64 + threadIdx.x], b);
    }
}

// ---- histogram: ONE packed 64-bit atomic per edge; returned old value gives rank ----
__global__ void hist_kernel(const int* __restrict__ col, const float* __restrict__ ew,
                            unsigned long long* __restrict__ pack, int* __restrict__ rank) {
    int e = blockIdx.x * blockDim.x + threadIdx.x;
    if (e >= N_EDGES) return;
    int c = col[e];
    unsigned fx = __float2uint_rn(ew[e] * FIX_SCALE);
    unsigned long long old = atomicAdd(&pack[c], (1ULL << 32) | (unsigned long long)fx);
    rank[e] = (int)(old >> 32);
}

// ---- decode pack -> dinv; derive BN affine a,b into ab[0..63],ab[64..127] ----
__global__ void dinv_ab_kernel(const unsigned long long* __restrict__ pack,
                               float* __restrict__ dinv, const float* __restrict__ sums,
                               const float* __restrict__ gamma, const float* __restrict__ beta,
                               float* __restrict__ ab) {
    int n = blockIdx.x * blockDim.x + threadIdx.x;
    if (n < 64) {
        float mu = sums[n] * (1.0f / N_NODES);
        float var = sums[64 + n] * (1.0f / N_NODES) - mu * mu;
        float inv = 1.0f / sqrtf(var + BN_EPS);
        float a = inv * gamma[n];
        ab[n] = a;
        ab[64 + n] = beta[n] - mu * a;
    }
    if (n < N_NODES) {
        unsigned low = (unsigned)(pack[n] & 0xFFFFFFFFULL);
        float d = 1.0f + (float)low * (1.0f / FIX_SCALE);   // self-loop weight 1 included
        dinv[n] = 1.0f / sqrtf(d);
    }
}

// ---- exclusive scan of cnt (pack high words) -> off, 1024 elems/block ----
__global__ void scan1_kernel(const unsigned long long* __restrict__ pack, int* __restrict__ off,
                             int* __restrict__ bsum) {
    __shared__ int lds[256];
    int tid = threadIdx.x;
    int base = blockIdx.x * 1024 + tid * 4;
    int c0 = (base + 0 < N_NODES) ? (int)(pack[base + 0] >> 32) : 0;
    int c1 = (base + 1 < N_NODES) ? (int)(pack[base + 1] >> 32) : 0;
    int c2 = (base + 2 < N_NODES) ? (int)(pack[base + 2] >> 32) : 0;
    int c3 = (base + 3 < N_NODES) ? (int)(pack[base + 3] >> 32) : 0;
    int tsum = c0 + c1 + c2 + c3;
    lds[tid] = tsum;
    __syncthreads();
    for (int d = 1; d < 256; d <<= 1) {
        int v = (tid >= d) ? lds[tid - d] : 0;
        __syncthreads();
        lds[tid] += v;
        __syncthreads();
    }
    int excl = lds[tid] - tsum;
    if (base + 0 < N_NODES) off[base + 0] = excl;
    if (base + 1 < N_NODES) off[base + 1] = excl + c0;
    if (base + 2 < N_NODES) off[base + 2] = excl + c0 + c1;
    if (base + 3 < N_NODES) off[base + 3] = excl + c0 + c1 + c2;
    if (tid == 255) bsum[blockIdx.x] = lds[255];
}

// ---- scan of block sums (nb <= 128), one block ----
__global__ void scan2_kernel(int* __restrict__ bsum, int nb) {
    __shared__ int lds[128];
    int tid = threadIdx.x;
    int v = (tid < nb) ? bsum[tid] : 0;
    lds[tid] = v;
    __syncthreads();
    for (int d = 1; d < 128; d <<= 1) {
        int u = (tid >= d) ? lds[tid - d] : 0;
        __syncthreads();
        lds[tid] += u;
        __syncthreads();
    }
    if (tid < nb) bsum[tid] = lds[tid] - v;
}

__global__ void scan3_kernel(int* __restrict__ off, const int* __restrict__ bsum) {
    int idx = blockIdx.x * blockDim.x + threadIdx.x;
    if (idx < N_NODES) off[idx] = off[idx] + bsum[idx >> 10];
    if (idx == 0) off[N_NODES] = N_EDGES;
}

// ---- scatter (atomic-free): pos = off[col] + rank; rec[pos] = (row, coef) ----
__global__ void scatter_kernel(const int* __restrict__ row, const int* __restrict__ col,
                               const float* __restrict__ ew, const float* __restrict__ rank,
                               const float* __restrict__ dinv, const int* __restrict__ off,
                               int2* __restrict__ rec) {
    int e = blockIdx.x * blockDim.x + threadIdx.x;
    if (e >= N_EDGES) return;
    int c = col[e], r = row[e];
    float coef = dinv[r] * ew[e] * dinv[c];
    int pos = off[c] + ((const int*)rank)[e];
    rec[pos] = make_int2(r, __float_as_int(coef));
}

// ---- gather with BN folded in: h = a*(sum coef*x) + b*(sum coef); 4-way unroll ----
__global__ void h_gather_kernel(const int2* __restrict__ rec, const int* __restrict__ off,
                                const float* __restrict__ dinv, const float* __restrict__ x,
                                const float* __restrict__ ab, float* __restrict__ h) {
    int n = blockIdx.x * 4 + (threadIdx.x >> 6);
    int ch = threadIdx.x & 63;
    int e0 = off[n], e1 = off[n + 1];
    float dv = dinv[n];
    float cself = dv * dv;
    float acc0 = cself * x[n * 64 + ch], acc1 = 0.0f, acc2 = 0.0f, acc3 = 0.0f;
    float csr = cself;
    int e = e0;
    for (; e + 4 <= e1; e += 4) {
        int2 r0 = rec[e], r1 = rec[e + 1], r2 = rec[e + 2], r3 = rec[e + 3];
        float c0 = __int_as_float(r0.y), c1 = __int_as_float(r1.y);
        float c2 = __int_as_float(r2.y), c3 = __int_as_float(r3.y);
        float x0 = x[(size_t)r0.x * 64 + ch], x1 = x[(size_t)r1.x * 64 + ch];
        float x2 = x[(size_t)r2.x * 64 + ch], x3 = x[(size_t)r3.x * 64 + ch];
        acc0 += c0 * x0; acc1 += c1 * x1; acc2 += c2 * x2; acc3 += c3 * x3;
        csr += c0 + c1 + c2 + c3;
    }
    for (; e < e1; ++e) {
        int2 rc = rec[e];
        float c = __int_as_float(rc.y);
        acc0 += c * x[(size_t)rc.x * 64 + ch];
        csr += c;
    }
    float acc = (acc0 + acc1) + (acc2 + acc3);
    h[n * 64 + ch] = ab[ch] * acc + ab[64 + ch] * csr;
}

// ---- graph segment offsets via binary search (batch is sorted) ----
__global__ void gstart_kernel(const int* __restrict__ batch, int* __restrict__ gstart) {
    int g = blockIdx.x * blockDim.x + threadIdx.x;
    if (g > N_GRAPHS) return;
    int lo = 0, hi = N_NODES;
    while (lo < hi) { int mid = (lo + hi) >> 1; if (batch[mid] < g) lo = mid + 1; else hi = mid; }
    gstart[g] = lo;
}

// ---- per-graph sums of raw x and of h (atomic partials) ----
__global__ void gsum_kernel(const float* __restrict__ x, const float* __restrict__ h,
                            const int* __restrict__ gstart, float* __restrict__ xsum,
                            float* __restrict__ hsum) {
    int g = blockIdx.x / NSPLIT, sp = blockIdx.x % NSPLIT;
    int s0g = gstart[g], s1g = gstart[g + 1];
    int len = s1g - s0g;
    int q = (len + NSPLIT - 1) / NSPLIT;
    int a0 = s0g + sp * q, a1 = min(s1g, a0 + q);
    int ch = threadIdx.x & 63, rg = threadIdx.x >> 6;
    float ax = 0.0f, ah = 0.0f;
    for (int n = a0 + rg; n < a1; n += 4) { ax += x[n * 64 + ch]; ah += h[n * 64 + ch]; }
    __shared__ float lx[4][64], lh[4][64];
    lx[rg][ch] = ax; lh[rg][ch] = ah;
    __syncthreads();
    if (threadIdx.x < 64) {
        int c = threadIdx.x;
        float sx = lx[0][c] + lx[1][c] + lx[2][c] + lx[3][c];
        float sh = lh[0][c] + lh[1][c] + lh[2][c] + lh[3][c];
        atomicAdd(&xsum[g * 64 + c], sx);
        atomicAdd(&hsum[g * 64 + c], sh);
    }
}

// ---- WT[t][o][i] = W[t][i][o] ----
__global__ void wt_prep_kernel(const float* __restrict__ W, float* __restrict__ WT) {
    int idx = blockIdx.x * blockDim.x + threadIdx.x;
    if (idx >= T_CAPS * 64 * 64) return;
    int t = idx >> 12, rem = idx & 4095, o = rem >> 6, i = rem & 63;
    WT[idx] = W[t * 4096 + i * 64 + o];
}

// ---- fused routing: thread-parallel logit dot + in-register softmax + accumulate.
//      mode 0: logits = h.wva + bva.  mode 1: logits = (h.wva + bva) + (h.wvb + bvb). ----
__global__ void ka_fused_kernel(const float* __restrict__ h, const int* __restrict__ gstart,
                                const float* __restrict__ wva, const float* __restrict__ bva,
                                const float* __restrict__ wvb, const float* __restrict__ bvb,
                                float* __restrict__ hc_part, float* __restrict__ csum_part,
                                int mode) {
    int g = blockIdx.x / NSPLIT, sp = blockIdx.x % NSPLIT;
    int s0g = gstart[g], s1g = gstart[g + 1];
    int len = s1g - s0g;
    int q = (len + NSPLIT - 1) / NSPLIT;
    int s0 = s0g + sp * q, s1 = min(s1g, s0 + q);
    int tid = threadIdx.x;
    int d = tid & 63, tg = tid >> 6;   // accumulate-phase mapping
    int t = tid & 15, kh = tid >> 4;   // dot-phase mapping

    __shared__ float hlds[CHUNK][65];
    __shared__ float wa[16][65];
    __shared__ float wb[16][65];
    __shared__ float clds[CHUNK][17];
    __shared__ float bvl[2][16];

    for (int i = tid; i < 16 * 64; i += 256) {
        int tt = i >> 6, dd = i & 63;
        wa[tt][dd] = wva[(g * 16 + tt) * 64 + dd];
        if (mode) wb[tt][dd] = wvb[(g * 16 + tt) * 64 + dd];
    }
    if (tid < 16) { bvl[0][tid] = bva[g * 16 + tid]; bvl[1][tid] = mode ? bvb[g * 16 + tid] : 0.0f; }
    for (int i = tid; i < CHUNK * 65; i += 256) ((float*)hlds)[i] = 0.0f;
    __syncthreads();

    float acc0 = 0, acc1 = 0, acc2 = 0, acc3 = 0;
    float cs0 = 0, cs1 = 0, cs2 = 0, cs3 = 0;

    for (int n0 = s0; n0 < s1; n0 += CHUNK) {
        int nn = min(CHUNK, s1 - n0);
        #pragma unroll
        for (int j = 0; j < 8; j++) {
            int k = tg * 8 + j;
            if (k < nn) hlds[k][d] = h[(size_t)(n0 + k) * 64 + d];
        }
        __syncthreads();
        int k0 = kh, k1 = kh + 16;
        float u0, u1;
        if (mode) {
            float a0 = bvl[0][t], a1 = bvl[0][t], b0 = bvl[1][t], b1 = bvl[1][t];
            for (int dd = 0; dd < 64; dd++) {
                float wav = wa[t][dd], wbv = wb[t][dd];
                float h0 = hlds[k0][dd], h1 = hlds[k1][dd];
                a0 += h0 * wav; a1 += h1 * wav;
                b0 += h0 * wbv; b1 += h1 * wbv;
            }
            u0 = a0 + b0; u1 = a1 + b1;
        } else {
            float a0 = bvl[0][t], a1 = bvl[0][t];
            for (int dd = 0; dd < 64; dd++) {
                float wav = wa[t][dd];
                a0 += hlds[k0][dd] * wav; a1 += hlds[k1][dd] * wav;
            }
            u0 = a0; u1 = a1;
        }
        float m0 = u0, m1 = u1;
        #pragma unroll
        for (int msk = 1; msk < 16; msk <<= 1) {
            m0 = fmaxf(m0, __shfl_xor(m0, msk, 64));
            m1 = fmaxf(m1, __shfl_xor(m1, msk, 64));
        }
        float e0 = expf(u0 - m0), e1 = expf(u1 - m1);
        float z0 = e0, z1 = e1;
        #pragma unroll
        for (int msk = 1; msk < 16; msk <<= 1) {
            z0 += __shfl_xor(z0, msk, 64);
            z1 += __shfl_xor(z1, msk, 64);
        }
        if (k0 < nn) clds[k0][t] = e0 / z0;
        if (k1 < nn) clds[k1][t] = e1 / z1;
        __syncthreads();
        for (int k = 0; k < nn; k++) {
            float hv = hlds[k][d];
            float c0 = clds[k][tg * 4 + 0], c1 = clds[k][tg * 4 + 1];
            float c2 = clds[k][tg * 4 + 2], c3 = clds[k][tg * 4 + 3];
            acc0 += c0 * hv; acc1 += c1 * hv; acc2 += c2 * hv; acc3 += c3 * hv;
            if (d == 0) { cs0 += c0; cs1 += c1; cs2 += c2; cs3 += c3; }
        }
        __syncthreads();
    }
    size_t base = ((size_t)(sp * N_GRAPHS + g) * 16 + tg * 4) * 64 + d;
    hc_part[base] = acc0; hc_part[base + 64] = acc1;
    hc_part[base + 128] = acc2; hc_part[base + 192] = acc3;
    if (d == 0) {
        int cb = (sp * N_GRAPHS + g) * 16 + tg * 4;
        csum_part[cb + 0] = cs0; csum_part[cb + 1] = cs1;
        csum_part[cb + 2] = cs2; csum_part[cb + 3] = cs3;
    }
}

// ---- kb: one wave per (g,t). mode 0: uniform-softmax path; 1: mid; 2: final+out ----
__global__ void kb_kernel(const float* __restrict__ hsum, const float* __restrict__ hc_part,
                          const float* __restrict__ csum_part, const float* __restrict__ W,
                          const float* __restrict__ WT, const float* __restrict__ bias,
                          const float* __restrict__ xsum, const float* __restrict__ ab,
                          const int* __restrict__ gstart, float* __restrict__ wv,
                          float* __restrict__ bv, float* __restrict__ out, int mode) {
    int wid = blockIdx.x * 4 + (threadIdx.x >> 6);
    int lane = threadIdx.x & 63;
    int g = wid >> 4, t = wid & 15;
    const float* Wt = W + t * 4096;
    float cnt = (float)(gstart[g + 1] - gstart[g]);
    float s;
    if (mode == 0) {
        const float* hr = hsum + g * 64;
        float acc = cnt * bias[t * 64 + lane];
        for (int i = 0; i < 64; i++) acc += hr[i] * Wt[i * 64 + lane];
        s = acc * (1.0f / 16.0f);
    } else {
        float csum = 0.0f;
        #pragma unroll
        for (int sp = 0; sp < NSPLIT; sp++) csum += csum_part[(sp * N_GRAPHS + g) * 16 + t];
        float acc = csum * bias[t * 64 + lane];
        for (int i = 0; i < 64; i++) {
            float hci = 0.0f;
            #pragma unroll
            for (int sp = 0; sp < NSPLIT; sp++)
                hci += hc_part[((size_t)(sp * N_GRAPHS + g) * 16 + t) * 64 + i];
            acc += hci * Wt[i * 64 + lane];
        }
        s = acc;
        if (mode == 2) {
            float xm = ab[lane] * xsum[g * 64 + lane] / fmaxf(cnt, 1.0f) + ab[64 + lane];
            s += xm;
        }
    }
    float sq = waveReduceSum(s * s);
    float scale = (sq / (1.0f + sq)) / sqrtf(sq + 1e-16f);
    float v = scale * s;
    if (mode == 2) {
        float tot = waveReduceSum(1.0f / fabsf(v));
        if (lane == 0) out[wid] = 1.0f / tot;
    } else {
        __shared__ float vlds[4][64];
        int w = threadIdx.x >> 6;
        vlds[w][lane] = v;
        __syncthreads();
        const float* WTt = WT + t * 4096;
        float acc = 0.0f;
        for (int o = 0; o < 64; o++) acc += WTt[o * 64 + lane] * vlds[w][o];
        wv[(size_t)wid * 64 + lane] = acc;
        float b = waveReduceSum(bias[t * 64 + lane] * v);
        if (lane == 0) bv[wid] = b;
    }
}

extern "C" void kernel_launch(void* const* d_in, const int* in_sizes, int n_in,
                              void* d_out, int out_size, void* d_ws, size_t ws_size,
                              hipStream_t stream) {
    const float* x     = (const float*)d_in[0];
    const int*   ei    = (const int*)d_in[1];
    const float* ew    = (const float*)d_in[2];
    const int*   batch = (const int*)d_in[3];
    const float* gamma = (const float*)d_in[4];
    const float* beta  = (const float*)d_in[5];
    const float* W     = (const float*)d_in[6];
    const float* bias  = (const float*)d_in[7];
    float* out = (float*)d_out;

    const int* row = ei;
    const int* col = ei + N_EDGES;

    char* basep = (char*)d_ws;
    int2* rec = (int2*)basep;                        basep += sizeof(int2) * N_EDGES;
    unsigned long long* pack = (unsigned long long*)basep; basep += 8ULL * N_NODES;
    float* p = (float*)basep;
    float* h        = p; p += (size_t)N_NODES * D_CH;
    float* hc_part  = p; p += (size_t)NSPLIT * N_GRAPHS * T_CAPS * D_CH;
    float* csum_part= p; p += NSPLIT * N_GRAPHS * T_CAPS;
    float* wva      = p; p += N_GRAPHS * T_CAPS * D_CH;
    float* bva      = p; p += N_GRAPHS * T_CAPS;
    float* wvb      = p; p += N_GRAPHS * T_CAPS * D_CH;
    float* bvb      = p; p += N_GRAPHS * T_CAPS;
    float* WT       = p; p += T_CAPS * 64 * 64;
    float* dinv     = p; p += N_NODES;
    float* bn_sums  = p; p += 128;
    float* ab       = p; p += 128;
    float* hsum     = p; p += N_GRAPHS * D_CH;
    float* xsum     = p; p += N_GRAPHS * D_CH;
    int*   ip       = (int*)p;
    int*   off      = ip; ip += N_NODES + 1;
    int*   rank     = ip; ip += N_EDGES;
    int*   bsum     = ip; ip += 128;
    int*   gstart   = ip; ip += N_GRAPHS + 1;

    const int nscan = (N_NODES + 1023) / 1024;

    init_kernel<<<(N_NODES + 255) / 256, 256, 0, stream>>>(pack, bn_sums, hsum, xsum);
    gstart_kernel<<<2, 256, 0, stream>>>(batch, gstart);
    bn_stats_kernel<<<512, 256, 0, stream>>>(x, bn_sums);
    hist_kernel<<<(N_EDGES + 255) / 256, 256, 0, stream>>>(col, ew, pack, rank);
    dinv_ab_kernel<<<(N_NODES + 255) / 256, 256, 0, stream>>>(pack, dinv, bn_sums, gamma, beta, ab);
    scan1_kernel<<<nscan, 256, 0, stream>>>(pack, off, bsum);
    scan2_kernel<<<1, 128, 0, stream>>>(bsum, nscan);
    scan3_kernel<<<(N_NODES + 255) / 256, 256, 0, stream>>>(off, bsum);
    scatter_kernel<<<(N_EDGES + 255) / 256, 256, 0, stream>>>(row, col, ew, (const float*)rank,
                                                              dinv, off, rec);
    h_gather_kernel<<<N_NODES / 4, 256, 0, stream>>>(rec, off, dinv, x, ab, h);
    gsum_kernel<<<N_GRAPHS * NSPLIT, 256, 0, stream>>>(x, h, gstart, xsum, hsum);
    wt_prep_kernel<<<(T_CAPS * 64 * 64 + 255) / 256, 256, 0, stream>>>(W, WT);

    kb_kernel<<<N_GRAPHS * T_CAPS / 4, 256, 0, stream>>>(hsum, hc_part, csum_part, W, WT, bias,
                                                          xsum, ab, gstart, wva, bva, out, 0);
    ka_fused_kernel<<<N_GRAPHS * NSPLIT, 256, 0, stream>>>(h, gstart, wva, bva, wvb, bvb,
                                                            hc_part, csum_part, 0);
    kb_kernel<<<N_GRAPHS * T_CAPS / 4, 256, 0, stream>>>(hsum, hc_part, csum_part, W, WT, bias,
                                                          xsum, ab, gstart, wvb, bvb, out, 1);
    ka_fused_kernel<<<N_GRAPHS * NSPLIT, 256, 0, stream>>>(h, gstart, wva, bva, wvb, bvb,
                                                            hc_part, csum_part, 1);
    kb_kernel<<<N_GRAPHS * T_CAPS / 4, 256, 0, stream>>>(hsum, hc_part, csum_part, W, WT, bias,
                                                          xsum, ab, gstart, wva, bva, out, 2);
}

// Round 6
// 341.786 us; speedup vs baseline: 2.5260x; 1.0605x over previous
//
#include <hip/hip_runtime.h>
#include <hip/hip_fp16.h>
#include <math.h>

#define N_NODES 100000
#define N_EDGES 1600000
#define N_GRAPHS 256
#define T_CAPS 16
#define D_CH 64
#define BN_EPS 1e-5f
#define NSPLIT 8
#define CHUNK 32
#define FIX_SCALE 33554432.0f   // 2^25

__device__ __forceinline__ float waveReduceSum(float v) {
    for (int m = 32; m >= 1; m >>= 1) v += __shfl_xor(v, m, 64);
    return v;
}

// ---- setup: pack=0, zero bn_sums/hsum/xsum, WT transpose, gstart binary search ----
__global__ void setup_kernel(unsigned long long* pack, float* bn_sums, float* hsum, float* xsum,
                             const float* __restrict__ W, float* __restrict__ WT,
                             const int* __restrict__ batch, int* __restrict__ gstart) {
    int idx = blockIdx.x * blockDim.x + threadIdx.x;
    if (idx < N_NODES) pack[idx] = 0ULL;
    if (idx < 128) bn_sums[idx] = 0.0f;
    if (idx < N_GRAPHS * D_CH) { hsum[idx] = 0.0f; xsum[idx] = 0.0f; }
    if (idx < T_CAPS * 64 * 64) {
        int t = idx >> 12, rem = idx & 4095, o = rem >> 6, i = rem & 63;
        WT[idx] = W[t * 4096 + i * 64 + o];
    }
    if (idx <= N_GRAPHS) {
        int lo = 0, hi = N_NODES;
        while (lo < hi) { int mid = (lo + hi) >> 1; if (batch[mid] < idx) lo = mid + 1; else hi = mid; }
        gstart[idx] = lo;
    }
}

// ---- BN stats + fp16 staging of x ----
__global__ void bn_stats_kernel(const float* __restrict__ x, float* __restrict__ sums,
                                __half2* __restrict__ x16) {
    int pr = threadIdx.x & 31;   // channel pair 0..31
    int rg = threadIdx.x >> 5;   // 0..7
    int c0 = pr * 2;
    float s0 = 0, q0 = 0, s1 = 0, q1 = 0;
    for (int r = blockIdx.x * 8 + rg; r < N_NODES; r += gridDim.x * 8) {
        float2 v = *(const float2*)(x + (size_t)r * 64 + c0);
        s0 += v.x; q0 += v.x * v.x;
        s1 += v.y; q1 += v.y * v.y;
        x16[(size_t)r * 32 + pr] = __floats2half2_rn(v.x, v.y);
    }
    __shared__ float ls[2][8][64];
    ls[0][rg][c0] = s0; ls[0][rg][c0 + 1] = s1;
    ls[1][rg][c0] = q0; ls[1][rg][c0 + 1] = q1;
    __syncthreads();
    if (threadIdx.x < 64) {
        float a = 0.0f, b = 0.0f;
        for (int i = 0; i < 8; i++) { a += ls[0][i][threadIdx.x]; b += ls[1][i][threadIdx.x]; }
        atomicAdd(&sums[threadIdx.x], a);
        atomicAdd(&sums[64 + threadIdx.x], b);
    }
}

// ---- histogram: ONE packed 64-bit atomic per edge; returned old value gives rank ----
__global__ void hist_kernel(const int* __restrict__ col, const float* __restrict__ ew,
                            unsigned long long* __restrict__ pack, int* __restrict__ rank) {
    int e = blockIdx.x * blockDim.x + threadIdx.x;
    if (e >= N_EDGES) return;
    int c = col[e];
    unsigned fx = __float2uint_rn(ew[e] * FIX_SCALE);
    unsigned long long old = atomicAdd(&pack[c], (1ULL << 32) | (unsigned long long)fx);
    rank[e] = (int)(old >> 32);
}

// ---- scan (1024/block) + dinv decode + BN affine ab ----
__global__ void scan1_kernel(const unsigned long long* __restrict__ pack, int* __restrict__ off,
                             int* __restrict__ bsum, float* __restrict__ dinv,
                             const float* __restrict__ sums, const float* __restrict__ gamma,
                             const float* __restrict__ beta, float* __restrict__ ab) {
    __shared__ int lds[256];
    int tid = threadIdx.x;
    int base = blockIdx.x * 1024 + tid * 4;
    int c[4];
    #pragma unroll
    for (int i = 0; i < 4; i++) {
        if (base + i < N_NODES) {
            unsigned long long pv = pack[base + i];
            c[i] = (int)(pv >> 32);
            float d = 1.0f + (float)(unsigned)(pv & 0xFFFFFFFFULL) * (1.0f / FIX_SCALE);
            dinv[base + i] = 1.0f / sqrtf(d);
        } else c[i] = 0;
    }
    if (blockIdx.x == 0 && tid < 64) {
        float mu = sums[tid] * (1.0f / N_NODES);
        float var = sums[64 + tid] * (1.0f / N_NODES) - mu * mu;
        float inv = 1.0f / sqrtf(var + BN_EPS);
        float a = inv * gamma[tid];
        ab[tid] = a;
        ab[64 + tid] = beta[tid] - mu * a;
    }
    int tsum = c[0] + c[1] + c[2] + c[3];
    lds[tid] = tsum;
    __syncthreads();
    for (int d = 1; d < 256; d <<= 1) {
        int v = (tid >= d) ? lds[tid - d] : 0;
        __syncthreads();
        lds[tid] += v;
        __syncthreads();
    }
    int excl = lds[tid] - tsum;
    if (base + 0 < N_NODES) off[base + 0] = excl;
    if (base + 1 < N_NODES) off[base + 1] = excl + c[0];
    if (base + 2 < N_NODES) off[base + 2] = excl + c[0] + c[1];
    if (base + 3 < N_NODES) off[base + 3] = excl + c[0] + c[1] + c[2];
    if (tid == 255) bsum[blockIdx.x] = lds[255];
}

// ---- scan of block sums (nb <= 128), one block ----
__global__ void scan2_kernel(int* __restrict__ bsum, int nb) {
    __shared__ int lds[128];
    int tid = threadIdx.x;
    int v = (tid < nb) ? bsum[tid] : 0;
    lds[tid] = v;
    __syncthreads();
    for (int d = 1; d < 128; d <<= 1) {
        int u = (tid >= d) ? lds[tid - d] : 0;
        __syncthreads();
        lds[tid] += u;
        __syncthreads();
    }
    if (tid < nb) bsum[tid] = lds[tid] - v;
}

__global__ void scan3_kernel(int* __restrict__ off, const int* __restrict__ bsum) {
    int idx = blockIdx.x * blockDim.x + threadIdx.x;
    if (idx < N_NODES) off[idx] = off[idx] + bsum[idx >> 10];
    if (idx == 0) off[N_NODES] = N_EDGES;
}

// ---- scatter (atomic-free): pos = off[col] + rank; rec[pos] = (row, coef) ----
__global__ void scatter_kernel(const int* __restrict__ row, const int* __restrict__ col,
                               const float* __restrict__ ew, const int* __restrict__ rank,
                               const float* __restrict__ dinv, const int* __restrict__ off,
                               int2* __restrict__ rec) {
    int e = blockIdx.x * blockDim.x + threadIdx.x;
    if (e >= N_EDGES) return;
    int c = col[e], r = row[e];
    float coef = dinv[r] * ew[e] * dinv[c];
    int pos = off[c] + rank[e];
    rec[pos] = make_int2(r, __float_as_int(coef));
}

// ---- gather (fp16 x): h = a*(sum coef*x) + b*(sum coef); 4-way unroll ----
__global__ void h_gather_kernel(const int2* __restrict__ rec, const int* __restrict__ off,
                                const float* __restrict__ dinv, const __half* __restrict__ x16,
                                const float* __restrict__ ab, float* __restrict__ h) {
    int n = blockIdx.x * 4 + (threadIdx.x >> 6);
    int ch = threadIdx.x & 63;
    int e0 = off[n], e1 = off[n + 1];
    float dv = dinv[n];
    float cself = dv * dv;
    float acc0 = cself * __half2float(x16[(size_t)n * 64 + ch]);
    float acc1 = 0.0f, acc2 = 0.0f, acc3 = 0.0f;
    float csr = cself;
    int e = e0;
    for (; e + 4 <= e1; e += 4) {
        int2 r0 = rec[e], r1 = rec[e + 1], r2 = rec[e + 2], r3 = rec[e + 3];
        float c0 = __int_as_float(r0.y), c1 = __int_as_float(r1.y);
        float c2 = __int_as_float(r2.y), c3 = __int_as_float(r3.y);
        float x0 = __half2float(x16[(size_t)r0.x * 64 + ch]);
        float x1 = __half2float(x16[(size_t)r1.x * 64 + ch]);
        float x2 = __half2float(x16[(size_t)r2.x * 64 + ch]);
        float x3 = __half2float(x16[(size_t)r3.x * 64 + ch]);
        acc0 += c0 * x0; acc1 += c1 * x1; acc2 += c2 * x2; acc3 += c3 * x3;
        csr += c0 + c1 + c2 + c3;
    }
    for (; e < e1; ++e) {
        int2 rc = rec[e];
        float c = __int_as_float(rc.y);
        acc0 += c * __half2float(x16[(size_t)rc.x * 64 + ch]);
        csr += c;
    }
    float acc = (acc0 + acc1) + (acc2 + acc3);
    h[(size_t)n * 64 + ch] = ab[ch] * acc + ab[64 + ch] * csr;
}

// ---- per-graph sums of x16 and of h (atomic partials) ----
__global__ void gsum_kernel(const __half* __restrict__ x16, const float* __restrict__ h,
                            const int* __restrict__ gstart, float* __restrict__ xsum,
                            float* __restrict__ hsum) {
    int g = blockIdx.x / NSPLIT, sp = blockIdx.x % NSPLIT;
    int s0g = gstart[g], s1g = gstart[g + 1];
    int len = s1g - s0g;
    int q = (len + NSPLIT - 1) / NSPLIT;
    int a0 = s0g + sp * q, a1 = min(s1g, a0 + q);
    int ch = threadIdx.x & 63, rg = threadIdx.x >> 6;
    float ax = 0.0f, ah = 0.0f;
    for (int n = a0 + rg; n < a1; n += 4) {
        ax += __half2float(x16[(size_t)n * 64 + ch]);
        ah += h[(size_t)n * 64 + ch];
    }
    __shared__ float lx[4][64], lh[4][64];
    lx[rg][ch] = ax; lh[rg][ch] = ah;
    __syncthreads();
    if (threadIdx.x < 64) {
        int c = threadIdx.x;
        float sx = lx[0][c] + lx[1][c] + lx[2][c] + lx[3][c];
        float sh = lh[0][c] + lh[1][c] + lh[2][c] + lh[3][c];
        atomicAdd(&xsum[g * 64 + c], sx);
        atomicAdd(&hsum[g * 64 + c], sh);
    }
}

// ---- fused routing: thread-parallel logit dot + in-register softmax + accumulate.
//      mode 0: logits = h.wva + bva.  mode 1: logits = (h.wva + bva) + (h.wvb + bvb). ----
__global__ void ka_fused_kernel(const float* __restrict__ h, const int* __restrict__ gstart,
                                const float* __restrict__ wva, const float* __restrict__ bva,
                                const float* __restrict__ wvb, const float* __restrict__ bvb,
                                float* __restrict__ hc_part, float* __restrict__ csum_part,
                                int mode) {
    int g = blockIdx.x / NSPLIT, sp = blockIdx.x % NSPLIT;
    int s0g = gstart[g], s1g = gstart[g + 1];
    int len = s1g - s0g;
    int q = (len + NSPLIT - 1) / NSPLIT;
    int s0 = s0g + sp * q, s1 = min(s1g, s0 + q);
    int tid = threadIdx.x;
    int d = tid & 63, tg = tid >> 6;
    int t = tid & 15, kh = tid >> 4;

    __shared__ float hlds[CHUNK][65];
    __shared__ float wa[16][65];
    __shared__ float wb[16][65];
    __shared__ float clds[CHUNK][17];
    __shared__ float bvl[2][16];

    for (int i = tid; i < 16 * 64; i += 256) {
        int tt = i >> 6, dd = i & 63;
        wa[tt][dd] = wva[(g * 16 + tt) * 64 + dd];
        if (mode) wb[tt][dd] = wvb[(g * 16 + tt) * 64 + dd];
    }
    if (tid < 16) { bvl[0][tid] = bva[g * 16 + tid]; bvl[1][tid] = mode ? bvb[g * 16 + tid] : 0.0f; }
    for (int i = tid; i < CHUNK * 65; i += 256) ((float*)hlds)[i] = 0.0f;
    __syncthreads();

    float acc0 = 0, acc1 = 0, acc2 = 0, acc3 = 0;
    float cs0 = 0, cs1 = 0, cs2 = 0, cs3 = 0;

    for (int n0 = s0; n0 < s1; n0 += CHUNK) {
        int nn = min(CHUNK, s1 - n0);
        #pragma unroll
        for (int j = 0; j < 8; j++) {
            int k = tg * 8 + j;
            if (k < nn) hlds[k][d] = h[(size_t)(n0 + k) * 64 + d];
        }
        __syncthreads();
        int k0 = kh, k1 = kh + 16;
        float u0, u1;
        if (mode) {
            float a0 = bvl[0][t], a1 = bvl[0][t], b0 = bvl[1][t], b1 = bvl[1][t];
            for (int dd = 0; dd < 64; dd++) {
                float wav = wa[t][dd], wbv = wb[t][dd];
                float h0 = hlds[k0][dd], h1 = hlds[k1][dd];
                a0 += h0 * wav; a1 += h1 * wav;
                b0 += h0 * wbv; b1 += h1 * wbv;
            }
            u0 = a0 + b0; u1 = a1 + b1;
        } else {
            float a0 = bvl[0][t], a1 = bvl[0][t];
            for (int dd = 0; dd < 64; dd++) {
                float wav = wa[t][dd];
                a0 += hlds[k0][dd] * wav; a1 += hlds[k1][dd] * wav;
            }
            u0 = a0; u1 = a1;
        }
        float m0 = u0, m1 = u1;
        #pragma unroll
        for (int msk = 1; msk < 16; msk <<= 1) {
            m0 = fmaxf(m0, __shfl_xor(m0, msk, 64));
            m1 = fmaxf(m1, __shfl_xor(m1, msk, 64));
        }
        float e0 = expf(u0 - m0), e1 = expf(u1 - m1);
        float z0 = e0, z1 = e1;
        #pragma unroll
        for (int msk = 1; msk < 16; msk <<= 1) {
            z0 += __shfl_xor(z0, msk, 64);
            z1 += __shfl_xor(z1, msk, 64);
        }
        if (k0 < nn) clds[k0][t] = e0 / z0;
        if (k1 < nn) clds[k1][t] = e1 / z1;
        __syncthreads();
        for (int k = 0; k < nn; k++) {
            float hv = hlds[k][d];
            float c0 = clds[k][tg * 4 + 0], c1 = clds[k][tg * 4 + 1];
            float c2 = clds[k][tg * 4 + 2], c3 = clds[k][tg * 4 + 3];
            acc0 += c0 * hv; acc1 += c1 * hv; acc2 += c2 * hv; acc3 += c3 * hv;
            if (d == 0) { cs0 += c0; cs1 += c1; cs2 += c2; cs3 += c3; }
        }
        __syncthreads();
    }
    size_t base = ((size_t)(sp * N_GRAPHS + g) * 16 + tg * 4) * 64 + d;
    hc_part[base] = acc0; hc_part[base + 64] = acc1;
    hc_part[base + 128] = acc2; hc_part[base + 192] = acc3;
    if (d == 0) {
        int cb = (sp * N_GRAPHS + g) * 16 + tg * 4;
        csum_part[cb + 0] = cs0; csum_part[cb + 1] = cs1;
        csum_part[cb + 2] = cs2; csum_part[cb + 3] = cs3;
    }
}

// ---- kb: one wave per (g,t). mode 0: uniform-softmax path; 1: mid; 2: final+out ----
__global__ void kb_kernel(const float* __restrict__ hsum, const float* __restrict__ hc_part,
                          const float* __restrict__ csum_part, const float* __restrict__ W,
                          const float* __restrict__ WT, const float* __restrict__ bias,
                          const float* __restrict__ xsum, const float* __restrict__ ab,
                          const int* __restrict__ gstart, float* __restrict__ wv,
                          float* __restrict__ bv, float* __restrict__ out, int mode) {
    int wid = blockIdx.x * 4 + (threadIdx.x >> 6);
    int lane = threadIdx.x & 63;
    int g = wid >> 4, t = wid & 15;
    const float* Wt = W + t * 4096;
    float cnt = (float)(gstart[g + 1] - gstart[g]);
    float s;
    if (mode == 0) {
        const float* hr = hsum + g * 64;
        float acc = cnt * bias[t * 64 + lane];
        for (int i = 0; i < 64; i++) acc += hr[i] * Wt[i * 64 + lane];
        s = acc * (1.0f / 16.0f);
    } else {
        float csum = 0.0f;
        #pragma unroll
        for (int sp = 0; sp < NSPLIT; sp++) csum += csum_part[(sp * N_GRAPHS + g) * 16 + t];
        float acc = csum * bias[t * 64 + lane];
        for (int i = 0; i < 64; i++) {
            float hci = 0.0f;
            #pragma unroll
            for (int sp = 0; sp < NSPLIT; sp++)
                hci += hc_part[((size_t)(sp * N_GRAPHS + g) * 16 + t) * 64 + i];
            acc += hci * Wt[i * 64 + lane];
        }
        s = acc;
        if (mode == 2) {
            float xm = ab[lane] * xsum[g * 64 + lane] / fmaxf(cnt, 1.0f) + ab[64 + lane];
            s += xm;
        }
    }
    float sq = waveReduceSum(s * s);
    float scale = (sq / (1.0f + sq)) / sqrtf(sq + 1e-16f);
    float v = scale * s;
    if (mode == 2) {
        float tot = waveReduceSum(1.0f / fabsf(v));
        if (lane == 0) out[wid] = 1.0f / tot;
    } else {
        __shared__ float vlds[4][64];
        int w = threadIdx.x >> 6;
        vlds[w][lane] = v;
        __syncthreads();
        const float* WTt = WT + t * 4096;
        float acc = 0.0f;
        for (int o = 0; o < 64; o++) acc += WTt[o * 64 + lane] * vlds[w][o];
        wv[(size_t)wid * 64 + lane] = acc;
        float b = waveReduceSum(bias[t * 64 + lane] * v);
        if (lane == 0) bv[wid] = b;
    }
}

extern "C" void kernel_launch(void* const* d_in, const int* in_sizes, int n_in,
                              void* d_out, int out_size, void* d_ws, size_t ws_size,
                              hipStream_t stream) {
    const float* x     = (const float*)d_in[0];
    const int*   ei    = (const int*)d_in[1];
    const float* ew    = (const float*)d_in[2];
    const int*   batch = (const int*)d_in[3];
    const float* gamma = (const float*)d_in[4];
    const float* beta  = (const float*)d_in[5];
    const float* W     = (const float*)d_in[6];
    const float* bias  = (const float*)d_in[7];
    float* out = (float*)d_out;

    const int* row = ei;
    const int* col = ei + N_EDGES;

    char* basep = (char*)d_ws;
    int2* rec = (int2*)basep;                              basep += sizeof(int2) * N_EDGES;
    unsigned long long* pack = (unsigned long long*)basep; basep += 8ULL * N_NODES;
    __half2* x16 = (__half2*)basep;                        basep += 2ULL * N_NODES * D_CH;
    float* p = (float*)basep;
    float* h        = p; p += (size_t)N_NODES * D_CH;
    float* hc_part  = p; p += (size_t)NSPLIT * N_GRAPHS * T_CAPS * D_CH;
    float* csum_part= p; p += NSPLIT * N_GRAPHS * T_CAPS;
    float* wva      = p; p += N_GRAPHS * T_CAPS * D_CH;
    float* bva      = p; p += N_GRAPHS * T_CAPS;
    float* wvb      = p; p += N_GRAPHS * T_CAPS * D_CH;
    float* bvb      = p; p += N_GRAPHS * T_CAPS;
    float* WT       = p; p += T_CAPS * 64 * 64;
    float* dinv     = p; p += N_NODES;
    float* bn_sums  = p; p += 128;
    float* ab       = p; p += 128;
    float* hsum     = p; p += N_GRAPHS * D_CH;
    float* xsum     = p; p += N_GRAPHS * D_CH;
    int*   ip       = (int*)p;
    int*   off      = ip; ip += N_NODES + 1;
    int*   rank     = ip; ip += N_EDGES;
    int*   bsum     = ip; ip += 128;
    int*   gstart   = ip; ip += N_GRAPHS + 1;

    const int nscan = (N_NODES + 1023) / 1024;

    setup_kernel<<<(N_NODES + 255) / 256, 256, 0, stream>>>(pack, bn_sums, hsum, xsum,
                                                             W, WT, batch, gstart);
    bn_stats_kernel<<<512, 256, 0, stream>>>(x, bn_sums, x16);
    hist_kernel<<<(N_EDGES + 255) / 256, 256, 0, stream>>>(col, ew, pack, rank);
    scan1_kernel<<<nscan, 256, 0, stream>>>(pack, off, bsum, dinv, bn_sums, gamma, beta, ab);
    scan2_kernel<<<1, 128, 0, stream>>>(bsum, nscan);
    scan3_kernel<<<(N_NODES + 255) / 256, 256, 0, stream>>>(off, bsum);
    scatter_kernel<<<(N_EDGES + 255) / 256, 256, 0, stream>>>(row, col, ew, rank, dinv, off, rec);
    h_gather_kernel<<<N_NODES / 4, 256, 0, stream>>>(rec, off, dinv, (const __half*)x16, ab, h);
    gsum_kernel<<<N_GRAPHS * NSPLIT, 256, 0, stream>>>((const __half*)x16, h, gstart, xsum, hsum);

    kb_kernel<<<N_GRAPHS * T_CAPS / 4, 256, 0, stream>>>(hsum, hc_part, csum_part, W, WT, bias,
                                                          xsum, ab, gstart, wva, bva, out, 0);
    ka_fused_kernel<<<N_GRAPHS * NSPLIT, 256, 0, stream>>>(h, gstart, wva, bva, wvb, bvb,
                                                            hc_part, csum_part, 0);
    kb_kernel<<<N_GRAPHS * T_CAPS / 4, 256, 0, stream>>>(hsum, hc_part, csum_part, W, WT, bias,
                                                          xsum, ab, gstart, wvb, bvb, out, 1);
    ka_fused_kernel<<<N_GRAPHS * NSPLIT, 256, 0, stream>>>(h, gstart, wva, bva, wvb, bvb,
                                                            hc_part, csum_part, 1);
    kb_kernel<<<N_GRAPHS * T_CAPS / 4, 256, 0, stream>>>(hsum, hc_part, csum_part, W, WT, bias,
                                                          xsum, ab, gstart, wva, bva, out, 2);
}